// Round 4
// baseline (416.875 us; speedup 1.0000x reference)
//
#include <hip/hip_runtime.h>

// row_attention_maxindex on MI355X — R9: 32 queries per wave in ra_flash.
// R8 counters: LDS data pipe = ~67% of duration (180K min cycles + 65K
// conflict cycles of 368K). phi/g tile reads are per-wave re-reads ->
// traffic scales with waves, not queries. 32q/wave (128q/block, grid 512)
// serves 2x output with the same phi/g reads: one phi read feeds both
// q-subtiles' QK MFMAs; one g read feeds 4 PV MFMAs. DS per query ~0.55x.
// Keeps R8's no-drain barriers, defer-max, pkrtz, single-buffer LDS.

typedef unsigned short u16;
typedef unsigned int   u32;
typedef float        floatx4 __attribute__((ext_vector_type(4)));
typedef unsigned int uintx4  __attribute__((ext_vector_type(4)));
typedef unsigned int uintx2  __attribute__((ext_vector_type(2)));
typedef _Float16     half8   __attribute__((ext_vector_type(8)));
typedef __fp16       fp16x2  __attribute__((ext_vector_type(2)));

#define HW 4096
#define CB 256
#define RP 128
#define EPSF 1e-5f

static __device__ __forceinline__ u16 f2bf(float f) {
  u32 u = __float_as_uint(f);
  u32 r = u + 0x7FFFu + ((u >> 16) & 1u);   // RNE
  return (u16)(r >> 16);
}
static __device__ __forceinline__ float bf2f(u16 h) {
  return __uint_as_float(((u32)h) << 16);
}
static __device__ __forceinline__ u16 f2h(float f) {
  _Float16 h = (_Float16)f;                 // RNE
  return __builtin_bit_cast(u16, h);
}
static __device__ __forceinline__ float h2f(u16 h) {
  return (float)__builtin_bit_cast(_Float16, h);
}
static __device__ __forceinline__ half8 as_h8(uintx4 v) {
  return __builtin_bit_cast(half8, v);
}
static __device__ __forceinline__ u32 pkrtz(float a, float b) {
  fp16x2 h = __builtin_amdgcn_cvt_pkrtz(a, b);
  return __builtin_bit_cast(u32, h);
}
// Barrier with DS-visibility only: does NOT drain vmcnt, so in-flight
// global prefetch loads survive across it.
static __device__ __forceinline__ void barrier_nodrain() {
  __builtin_amdgcn_sched_barrier(0);
  asm volatile("s_waitcnt lgkmcnt(0)" ::: "memory");
  __builtin_amdgcn_s_barrier();
  __builtin_amdgcn_sched_barrier(0);
}

union Pk8 { u16 u[8]; uintx4 v; };
union Pk4 { u16 u[4]; uintx2 v; };

// ---------------------------------------------------------------------------
// Mega-projection: 6 projections in one dispatch. blockIdx>>8 selects config.
// Block: 64 pos x 128 r, 256 threads, thread = 4 pos x 8 r. Output fp16.
// ---------------------------------------------------------------------------
struct ProjCfg {
  const float* x; const float* w; const float* bias;
  const float* add; const float* pre; u16* out;
  int wstride; int transposed;
};
struct ProjCfg6 { ProjCfg c[6]; };

__global__ __launch_bounds__(256) void ra_proj6(ProjCfg6 cfg)
{
  __shared__ float x_lds[32][68];
  __shared__ float w_lds[32][132];
  const ProjCfg C = cfg.c[blockIdx.x >> 8];
  const float* __restrict__ x    = C.x;
  const float* __restrict__ w    = C.w;
  const float* __restrict__ bias = C.bias;
  const float* __restrict__ addend = C.add;
  const float* __restrict__ pre  = C.pre;
  u16* __restrict__ outp = C.out;
  const int wstride = C.wstride;

  const int tid  = threadIdx.x;
  const int inner= blockIdx.x & 255;
  const int b    = inner >> 6;
  const int pos0 = (inner & 63) * 64;
  const int rt = tid & 15, pt = tid >> 4;

  float acc[4][8];
  #pragma unroll
  for (int i = 0; i < 4; i++)
    #pragma unroll
    for (int j = 0; j < 8; j++) acc[i][j] = 0.f;

  const int xc = tid >> 3, xp = (tid & 7) * 8;        // x staging
  const int wr_ = tid >> 1, wc_ = (tid & 1) * 16;     // w staging

  for (int cc = 0; cc < 8; ++cc) {
    {
      const float* xr = x + ((size_t)(b * CB + cc * 32 + xc)) * HW + pos0 + xp;
      floatx4 a0 = *(const floatx4*)xr;
      floatx4 a1 = *(const floatx4*)(xr + 4);
      *(floatx4*)&x_lds[xc][xp]     = a0;
      *(floatx4*)&x_lds[xc][xp + 4] = a1;
    }
    {
      const float* wp = w + (size_t)wr_ * wstride + cc * 32 + wc_;
      #pragma unroll
      for (int jj = 0; jj < 16; jj++) w_lds[wc_ + jj][wr_] = wp[jj];
    }
    __syncthreads();
    #pragma unroll 8
    for (int c = 0; c < 32; c++) {
      floatx4 xv = *(const floatx4*)&x_lds[c][pt * 4];
      floatx4 w0 = *(const floatx4*)&w_lds[c][rt * 8];
      floatx4 w1 = *(const floatx4*)&w_lds[c][rt * 8 + 4];
      #pragma unroll
      for (int i = 0; i < 4; i++) {
        acc[i][0] += xv[i] * w0[0]; acc[i][1] += xv[i] * w0[1];
        acc[i][2] += xv[i] * w0[2]; acc[i][3] += xv[i] * w0[3];
        acc[i][4] += xv[i] * w1[0]; acc[i][5] += xv[i] * w1[1];
        acc[i][6] += xv[i] * w1[2]; acc[i][7] += xv[i] * w1[3];
      }
    }
    __syncthreads();
  }

  if (pre) {  // extra channel 256: pre/128 * w[r][256]
    float wcol[8];
    #pragma unroll
    for (int j = 0; j < 8; j++) wcol[j] = w[(size_t)(rt * 8 + j) * wstride + 256];
    #pragma unroll
    for (int i = 0; i < 4; i++) {
      float pv = pre[(size_t)b * HW + pos0 + pt * 4 + i] * (1.f / 128.f);
      #pragma unroll
      for (int j = 0; j < 8; j++) acc[i][j] += pv * wcol[j];
    }
  }
  #pragma unroll
  for (int j = 0; j < 8; j++) {
    float bs = bias[rt * 8 + j];
    #pragma unroll
    for (int i = 0; i < 4; i++) acc[i][j] += bs;
  }
  if (addend) {  // addend[b][r][pos]
    #pragma unroll
    for (int j = 0; j < 8; j++) {
      floatx4 av = *(const floatx4*)(addend + (size_t)(b * RP + rt * 8 + j) * HW + pos0 + pt * 4);
      #pragma unroll
      for (int i = 0; i < 4; i++) acc[i][j] += av[i];
    }
  }

  if (!C.transposed) {  // out[b][pos][r]
    #pragma unroll
    for (int i = 0; i < 4; i++) {
      Pk8 pk;
      #pragma unroll
      for (int j = 0; j < 8; j++) pk.u[j] = f2h(acc[i][j]);
      *(uintx4*)(outp + (size_t)(b * HW + pos0 + pt * 4 + i) * RP + rt * 8) = pk.v;
    }
  } else {            // out[b][r][pos]
    #pragma unroll
    for (int j = 0; j < 8; j++) {
      Pk4 pk;
      #pragma unroll
      for (int i = 0; i < 4; i++) pk.u[i] = f2h(acc[i][j]);
      *(uintx2*)(outp + (size_t)(b * RP + rt * 8 + j) * HW + pos0 + pt * 4) = pk.v;
    }
  }
}

// ---------------------------------------------------------------------------
// Flash attention partials (both sides, split-K=2), transposed-S form.
// Block: (side, b, 128 q, split of 2048 keys), 4 waves x 32 q. 32 K-tiles of
// 64 keys, single-buffered LDS, 1-iter register prefetch, no-drain barriers.
// Per wave TWO q-subtiles (qt=0,1): one phi read feeds both QK MFMAs, one
// g read feeds 4 PV MFMAs -> ~0.55x LDS traffic per query vs 16q/wave.
// S^T[key][q] = mfma(A=phi, B=theta): D[row=quad*4+r = key][col=ln16 = q].
// after^T[v][q] = mfma(A=g, B=P): per-lane v=quad*4+r (x8 tiles), q=ln16.
// Online softmax with defer-max (THR=8); epilogue stores accO/l.
// ---------------------------------------------------------------------------
__global__ __launch_bounds__(256) void ra_flash(
    const u16* __restrict__ thetaL, const u16* __restrict__ phiTL,
    const u16* __restrict__ gTL,
    const u16* __restrict__ thetaR, const u16* __restrict__ phiTR,
    const u16* __restrict__ gTR,
    u16* __restrict__ pO, float* __restrict__ mla)
{
  __shared__ uintx4 phi_lds[16 * 65];    // [rchunk8 cb(16)][k(64)]
  __shared__ uintx4 g_lds[8 * 129];      // [kchunk8 kcb(8)][v(128)]
  __shared__ u16 P_lds[4][2][16 * 76];   // per-wave, per-qt [q(16)][k(64)]

  const int tid  = threadIdx.x;
  const int bx   = blockIdx.x;
  const int side = bx >> 8;
  const int sbx  = bx & 255;
  const u16* __restrict__ theta = side ? thetaR : thetaL;
  const u16* __restrict__ phiT  = side ? phiTR  : phiTL;
  const u16* __restrict__ gT    = side ? gTR    : gTL;

  const int b    = sbx >> 6;
  const int rem  = sbx & 63;
  const int q0   = (rem >> 1) * 128;
  const int split= rem & 1;
  const int kbase= split * 2048;
  const int wv   = tid >> 6;
  const int lane = tid & 63;
  const int ln16 = lane & 15;
  const int quad = lane >> 4;

  // theta fragments for both q-subtiles; B-operand: B[k=r][n=q=ln16]
  uintx4 aq[2][4];
  #pragma unroll
  for (int qt = 0; qt < 2; qt++) {
    const uintx4* tr = (const uintx4*)(theta + (size_t)(b * HW + q0 + wv * 32 + qt * 16 + ln16) * RP);
    #pragma unroll
    for (int c = 0; c < 4; c++) aq[qt][c] = tr[c * 4 + quad];
  }

  floatx4 accO[2][8];   // accO[qt][vt][r] = after^T[v=vt*16+quad*4+r][q]
  #pragma unroll
  for (int qt = 0; qt < 2; qt++)
    #pragma unroll
    for (int v = 0; v < 8; v++) accO[qt][v] = (floatx4)0.0f;
  float m_q[2] = {-3.0e38f, -3.0e38f};
  float l_q[2] = {0.f, 0.f};
  float aC_q[2] = {0.f, 0.f};

  const int sk  = tid >> 4, scb = tid & 15;  // phi staging
  const int gv_ = tid >> 3, gcb = tid & 7;   // g staging

  uintx4 sp[4], sg[4];
  #pragma unroll
  for (int i = 0; i < 4; i++) {
    sp[i] = *(const uintx4*)(phiT + (size_t)(b * HW + kbase + i * 16 + sk) * RP + scb * 8);
    sg[i] = *(const uintx4*)(gT + (size_t)(b * RP + i * 32 + gv_) * HW + kbase + gcb * 8);
  }

  #pragma unroll 1
  for (int j = 0; j < 32; j++) {
    #pragma unroll
    for (int i = 0; i < 4; i++) {
      phi_lds[scb * 65 + i * 16 + sk] = sp[i];
      g_lds[gcb * 129 + i * 32 + gv_] = sg[i];
    }
    if (j < 31) {  // prefetch next tile into regs; stays in flight (no drain)
      const int k0n = kbase + (j + 1) * 64;
      #pragma unroll
      for (int i = 0; i < 4; i++) {
        sp[i] = *(const uintx4*)(phiT + (size_t)(b * HW + k0n + i * 16 + sk) * RP + scb * 8);
        sg[i] = *(const uintx4*)(gT + (size_t)(b * RP + i * 32 + gv_) * HW + k0n + gcb * 8);
      }
    }
    barrier_nodrain();  // staged tile visible (lgkmcnt only, vmcnt alive)

    // S^T[64k x 16q] x2 subtiles; one phi read feeds both qt MFMAs.
    floatx4 sf[2][4];
    #pragma unroll
    for (int qt = 0; qt < 2; qt++)
      #pragma unroll
      for (int s = 0; s < 4; s++) sf[qt][s] = (floatx4)0.0f;
    __builtin_amdgcn_s_setprio(1);
    #pragma unroll
    for (int c = 0; c < 4; c++) {
      half8 b0 = as_h8(aq[0][c]);
      half8 b1 = as_h8(aq[1][c]);
      #pragma unroll
      for (int s = 0; s < 4; s++) {
        uintx4 ap = phi_lds[(c * 4 + quad) * 65 + s * 16 + ln16];
        sf[0][s] = __builtin_amdgcn_mfma_f32_16x16x32_f16(as_h8(ap), b0, sf[0][s], 0, 0, 0);
        sf[1][s] = __builtin_amdgcn_mfma_f32_16x16x32_f16(as_h8(ap), b1, sf[1][s], 0, 0, 0);
      }
    }
    __builtin_amdgcn_s_setprio(0);

    // per-lane online softmax (query = q-subtile qt, row ln16); defer-max.
    const float colbase = (float)((j * 64) & 127) + (float)(quad * 4);
    #pragma unroll
    for (int qt = 0; qt < 2; qt++) {
      float ms0 = fmaxf(fmaxf(sf[qt][0][0], sf[qt][0][1]), fmaxf(sf[qt][0][2], sf[qt][0][3]));
      float ms1 = fmaxf(fmaxf(sf[qt][1][0], sf[qt][1][1]), fmaxf(sf[qt][1][2], sf[qt][1][3]));
      float ms2 = fmaxf(fmaxf(sf[qt][2][0], sf[qt][2][1]), fmaxf(sf[qt][2][2], sf[qt][2][3]));
      float ms3 = fmaxf(fmaxf(sf[qt][3][0], sf[qt][3][1]), fmaxf(sf[qt][3][2], sf[qt][3][3]));
      float mx = fmaxf(fmaxf(ms0, ms1), fmaxf(ms2, ms3));
      mx = fmaxf(mx, __shfl_xor(mx, 16));
      mx = fmaxf(mx, __shfl_xor(mx, 32));
      if (__any(mx > m_q[qt] + 8.f)) {   // rare in steady state
        const float mnew  = fmaxf(m_q[qt], mx);
        const float alpha = __expf(m_q[qt] - mnew);
        m_q[qt] = mnew;
        l_q[qt] *= alpha; aC_q[qt] *= alpha;
        #pragma unroll
        for (int v = 0; v < 8; v++) accO[qt][v] *= alpha;
      }
      float ps = 0.f, pc = 0.f;
      #pragma unroll
      for (int s = 0; s < 4; s++) {
        float p0 = __expf(sf[qt][s][0] - m_q[qt]);
        float p1 = __expf(sf[qt][s][1] - m_q[qt]);
        float p2 = __expf(sf[qt][s][2] - m_q[qt]);
        float p3 = __expf(sf[qt][s][3] - m_q[qt]);
        ps += (p0 + p1) + (p2 + p3);
        const float cb = colbase + (float)(s * 16);
        pc += p0 * cb + p1 * (cb + 1.f) + p2 * (cb + 2.f) + p3 * (cb + 3.f);
        uintx2 pkv;
        pkv[0] = pkrtz(p0, p1);
        pkv[1] = pkrtz(p2, p3);
        *(uintx2*)&P_lds[wv][qt][ln16 * 76 + s * 16 + quad * 4] = pkv;
      }
      ps += __shfl_xor(ps, 16); ps += __shfl_xor(ps, 32);
      pc += __shfl_xor(pc, 16); pc += __shfl_xor(pc, 32);
      l_q[qt]  += ps;
      aC_q[qt] += pc;
    }

    // no barrier: P_lds is wave-private; DS ops are in-order per wave.
    half8 pb00 = as_h8(*(const uintx4*)&P_lds[wv][0][ln16 * 76 + quad * 8]);
    half8 pb01 = as_h8(*(const uintx4*)&P_lds[wv][0][ln16 * 76 + 32 + quad * 8]);
    half8 pb10 = as_h8(*(const uintx4*)&P_lds[wv][1][ln16 * 76 + quad * 8]);
    half8 pb11 = as_h8(*(const uintx4*)&P_lds[wv][1][ln16 * 76 + 32 + quad * 8]);
    __builtin_amdgcn_s_setprio(1);
    #pragma unroll
    for (int vt = 0; vt < 8; vt++) {
      half8 ag0 = as_h8(g_lds[quad * 129 + vt * 16 + ln16]);
      half8 ag1 = as_h8(g_lds[(4 + quad) * 129 + vt * 16 + ln16]);
      accO[0][vt] = __builtin_amdgcn_mfma_f32_16x16x32_f16(ag0, pb00, accO[0][vt], 0, 0, 0);
      accO[0][vt] = __builtin_amdgcn_mfma_f32_16x16x32_f16(ag1, pb01, accO[0][vt], 0, 0, 0);
      accO[1][vt] = __builtin_amdgcn_mfma_f32_16x16x32_f16(ag0, pb10, accO[1][vt], 0, 0, 0);
      accO[1][vt] = __builtin_amdgcn_mfma_f32_16x16x32_f16(ag1, pb11, accO[1][vt], 0, 0, 0);
    }
    __builtin_amdgcn_s_setprio(0);
    barrier_nodrain();  // all reads of this tile done before next overwrite
  }

  // epilogue: per lane two queries; store accO/l (fp16-safe with defer).
  #pragma unroll
  for (int qt = 0; qt < 2; qt++) {
    const int q = q0 + wv * 32 + qt * 16 + ln16;
    const size_t p = (size_t)side * 32768 + (size_t)split * 16384 + b * HW + q;
    u16* orow = pO + p * RP;
    const float invl = 1.f / l_q[qt];
    #pragma unroll
    for (int vt = 0; vt < 8; vt++) {
      uintx2 pkv;
      pkv[0] = pkrtz(accO[qt][vt][0] * invl, accO[qt][vt][1] * invl);
      pkv[1] = pkrtz(accO[qt][vt][2] * invl, accO[qt][vt][3] * invl);
      *(uintx2*)(orow + vt * 16 + quad * 4) = pkv;
    }
    if (quad == 0) {
      floatx4 m4; m4[0] = m_q[qt]; m4[1] = l_q[qt]; m4[2] = aC_q[qt]; m4[3] = 0.f;
      *(floatx4*)(mla + p * 4) = m4;
    }
  }
}

// ---------------------------------------------------------------------------
// Combine split-K partials (both sides): after (bf16) + index (fp32).
// pO holds accO/l per split => weight by w*l (identical math).
// Block 256 = 2 (side,query) pairs x 128 v. pp in [0, 32768).
// ---------------------------------------------------------------------------
__global__ __launch_bounds__(256) void ra_combine(
    const u16* __restrict__ pO, const float* __restrict__ mla,
    u16* __restrict__ afterL, u16* __restrict__ afterR,
    float* __restrict__ idxL, float* __restrict__ idxR)
{
  const int t = threadIdx.x;
  const int pp = blockIdx.x * 2 + (t >> 7);
  const int side = pp >> 14;
  const int p = pp & 16383;
  const int v = t & 127;
  const size_t base = (size_t)side * 32768;
  const floatx4 A  = *(const floatx4*)(mla + (base + p) * 4);
  const floatx4 Bv = *(const floatx4*)(mla + (base + 16384 + p) * 4);
  const float M  = fmaxf(A[0], Bv[0]);
  const float w0 = __expf(A[0] - M), w1 = __expf(Bv[0] - M);
  const float s0 = w0 * A[1], s1 = w1 * Bv[1];     // w * l
  const float inv = 1.0f / (s0 + s1);
  const float a0 = h2f(pO[(base + p) * RP + v]);
  const float a1 = h2f(pO[(base + 16384 + p) * RP + v]);
  u16* after = side ? afterR : afterL;
  after[(size_t)p * RP + v] = f2bf((s0 * a0 + s1 * a1) * inv);
  if (v == 0) {
    float* idx = side ? idxR : idxL;
    idx[p] = (float)(p & 127) - (w0 * A[2] + w1 * Bv[2]) * inv;
  }
}

// ---------------------------------------------------------------------------
// Up-projection (both sides): y[b,co,pos] = after[b,pos,:]·up_w[co,:] + up_b
// ---------------------------------------------------------------------------
__global__ __launch_bounds__(256) void ra_up(
    const u16* __restrict__ afterL, const u16* __restrict__ afterR,
    const float* __restrict__ w, const float* __restrict__ bias,
    u16* __restrict__ yL, u16* __restrict__ yR)
{
  __shared__ float x_lds[32][68];   // [r][pos]
  __shared__ float w_lds[32][132];  // [r][co]
  const int tid  = threadIdx.x;
  const int bx   = blockIdx.x;
  const int side = bx >> 9;
  const int sbx  = bx & 511;
  const u16* __restrict__ after = side ? afterR : afterL;
  u16* __restrict__ y = side ? yR : yL;
  const int b    = sbx >> 7;
  const int pos0 = ((sbx >> 1) & 63) * 64;
  const int hc   = sbx & 1;
  const int rt = tid & 15, pt = tid >> 4;

  float acc[4][8];
  #pragma unroll
  for (int i = 0; i < 4; i++)
    #pragma unroll
    for (int j = 0; j < 8; j++) acc[i][j] = 0.f;

  const int apos = tid >> 2, ars = (tid & 3) * 8;
  const int wr_ = tid >> 1, wc_ = (tid & 1) * 16;

  for (int cc = 0; cc < 4; ++cc) {
    {
      const u16* ar = after + (size_t)(b * HW + pos0 + apos) * RP + cc * 32 + ars;
      uintx4 raw = *(const uintx4*)ar;
      #pragma unroll
      for (int k = 0; k < 4; k++) {
        u32 wd = raw[k];
        x_lds[ars + 2 * k][apos]     = bf2f((u16)(wd & 0xffffu));
        x_lds[ars + 2 * k + 1][apos] = bf2f((u16)(wd >> 16));
      }
    }
    {
      const float* wp = w + (size_t)(hc * 128 + wr_) * RP + cc * 32 + wc_;
      #pragma unroll
      for (int jj = 0; jj < 16; jj++) w_lds[wc_ + jj][wr_] = wp[jj];
    }
    __syncthreads();
    #pragma unroll 8
    for (int c = 0; c < 32; c++) {
      floatx4 xv = *(const floatx4*)&x_lds[c][pt * 4];
      floatx4 w0 = *(const floatx4*)&w_lds[c][rt * 8];
      floatx4 w1 = *(const floatx4*)&w_lds[c][rt * 8 + 4];
      #pragma unroll
      for (int i = 0; i < 4; i++) {
        acc[i][0] += xv[i] * w0[0]; acc[i][1] += xv[i] * w0[1];
        acc[i][2] += xv[i] * w0[2]; acc[i][3] += xv[i] * w0[3];
        acc[i][4] += xv[i] * w1[0]; acc[i][5] += xv[i] * w1[1];
        acc[i][6] += xv[i] * w1[2]; acc[i][7] += xv[i] * w1[3];
      }
    }
    __syncthreads();
  }

  #pragma unroll
  for (int j = 0; j < 8; j++) {
    const int co = hc * 128 + rt * 8 + j;
    const float bs = bias[co];
    Pk4 pk;
    #pragma unroll
    for (int i = 0; i < 4; i++) pk.u[i] = f2bf(acc[i][j] + bs);
    *(uintx2*)(y + (size_t)(b * CB + co) * HW + pos0 + pt * 4) = pk.v;
  }
}

// ---------------------------------------------------------------------------
// Per-channel batch stats (both sides) over (B, HW): mean and rstd.
// ---------------------------------------------------------------------------
__global__ __launch_bounds__(256) void ra_stats(
    const u16* __restrict__ yL, const u16* __restrict__ yR,
    float* __restrict__ stL, float* __restrict__ stR)
{
  const int side = blockIdx.x >> 8;
  const int c = blockIdx.x & 255;
  const u16* __restrict__ y = side ? yR : yL;
  float* __restrict__ stats = side ? stR : stL;
  const int tid = threadIdx.x;
  float s = 0.f, sq = 0.f;
  for (int b = 0; b < 4; b++) {
    const uintx4* row = (const uintx4*)(y + (size_t)(b * CB + c) * HW);
    #pragma unroll
    for (int t = 0; t < 2; t++) {
      uintx4 rv = row[tid + t * 256];
      #pragma unroll
      for (int k = 0; k < 4; k++) {
        float a0 = bf2f((u16)(rv[k] & 0xffffu));
        float a1 = bf2f((u16)(rv[k] >> 16));
        s += a0 + a1; sq += a0 * a0 + a1 * a1;
      }
    }
  }
  #pragma unroll
  for (int m = 1; m < 64; m <<= 1) { s += __shfl_xor(s, m); sq += __shfl_xor(sq, m); }
  __shared__ float red[8];
  const int wv = tid >> 6;
  if ((tid & 63) == 0) { red[wv * 2] = s; red[wv * 2 + 1] = sq; }
  __syncthreads();
  if (tid == 0) {
    s  = red[0] + red[2] + red[4] + red[6];
    sq = red[1] + red[3] + red[5] + red[7];
    const float mean = s * (1.f / 16384.f);
    const float var  = sq * (1.f / 16384.f) - mean * mean;
    stats[2 * c]     = mean;
    stats[2 * c + 1] = rsqrtf(var + EPSF);
  }
}

// ---------------------------------------------------------------------------
// out = x + gamma*(y - mean)*rstd + beta  (both sides, float4)
// ---------------------------------------------------------------------------
__global__ __launch_bounds__(256) void ra_fin(
    const float* __restrict__ left, const float* __restrict__ right,
    const u16* __restrict__ yL, const u16* __restrict__ yR,
    const float* __restrict__ stL, const float* __restrict__ stR,
    const float* __restrict__ gamma, const float* __restrict__ beta,
    float* __restrict__ out)
{
  const size_t e = (size_t)blockIdx.x * 256 + threadIdx.x;  // global float4 idx
  const int side = (int)(e >> 20);
  const size_t e4 = e & 1048575;
  const int c = (int)((e4 >> 10) & 255);
  const float* x = side ? right : left;
  const u16* y = side ? yR : yL;
  const float* stats = side ? stR : stL;
  const float mean = stats[2 * c], rstd = stats[2 * c + 1];
  const float ga = gamma[c], be = beta[c];
  floatx4 xv = ((const floatx4*)x)[e4];
  uintx2 yv = ((const uintx2*)y)[e4];
  float f0 = bf2f((u16)(yv[0] & 0xffffu));
  float f1 = bf2f((u16)(yv[0] >> 16));
  float f2 = bf2f((u16)(yv[1] & 0xffffu));
  float f3 = bf2f((u16)(yv[1] >> 16));
  floatx4 o;
  o[0] = xv[0] + ga * ((f0 - mean) * rstd) + be;
  o[1] = xv[1] + ga * ((f1 - mean) * rstd) + be;
  o[2] = xv[2] + ga * ((f2 - mean) * rstd) + be;
  o[3] = xv[3] + ga * ((f3 - mean) * rstd) + be;
  ((floatx4*)out)[(size_t)side * 1048576 + e4] = o;
}

// ---------------------------------------------------------------------------
extern "C" void kernel_launch(void* const* d_in, const int* in_sizes, int n_in,
                              void* d_out, int out_size, void* d_ws, size_t ws_size,
                              hipStream_t stream)
{
  const float* left    = (const float*)d_in[0];
  const float* right   = (const float*)d_in[1];
  const float* pre_l   = (const float*)d_in[2];
  const float* pre_r   = (const float*)d_in[3];
  const float* query_l = (const float*)d_in[4];
  const float* key_l   = (const float*)d_in[5];
  const float* query_r = (const float*)d_in[6];
  const float* key_r   = (const float*)d_in[7];
  const float* theta_w = (const float*)d_in[8];
  const float* theta_b = (const float*)d_in[9];
  const float* phi_w   = (const float*)d_in[10];
  const float* phi_b   = (const float*)d_in[11];
  const float* g_w     = (const float*)d_in[12];
  const float* g_b     = (const float*)d_in[13];
  const float* up_w    = (const float*)d_in[14];
  const float* up_b    = (const float*)d_in[15];
  const float* bn_g    = (const float*)d_in[16];
  const float* bn_b    = (const float*)d_in[17];
  float* out = (float*)d_out;

  char* ws = (char*)d_ws;
  const size_t SZ = (size_t)4 * HW * RP * 2;  // 4 MiB (fp16 [4][4096][128])
  u16* thetaL = (u16*)(ws);
  u16* phiTL  = (u16*)(ws + 1 * SZ);
  u16* gTL    = (u16*)(ws + 2 * SZ);
  u16* thetaR = (u16*)(ws + 3 * SZ);
  u16* phiTR  = (u16*)(ws + 4 * SZ);
  u16* gTR    = (u16*)(ws + 5 * SZ);
  u16* afterL = (u16*)(ws + 6 * SZ);
  u16* afterR = (u16*)(ws + 7 * SZ);
  u16* pO     = (u16*)(ws + 8 * SZ);    // 16 MiB (2 sides x 2 splits), aliased w/ y
  u16* yL     = (u16*)(ws + 8 * SZ);    // 8 MiB (written after pO is consumed)
  u16* yR     = (u16*)(ws + 10 * SZ);   // 8 MiB
  float* stL  = (float*)(ws + 12 * SZ);
  float* stR  = (float*)(ws + 12 * SZ + 2048);
  float* mla  = (float*)(ws + 12 * SZ + 8192);  // 1 MiB (65536 x 4 fp32)

  dim3 blk(256);
  // side L: x_q=left, x_kv=right, query_l, key_r; side R mirrored.
  ProjCfg6 pc;
  pc.c[0] = { left,  theta_w, theta_b, query_l, pre_l,   thetaL, 257, 0 };
  pc.c[1] = { right, phi_w,   phi_b,   key_r,   nullptr, phiTL,  256, 0 };
  pc.c[2] = { right, g_w,     g_b,     nullptr, nullptr, gTL,    256, 1 };
  pc.c[3] = { right, theta_w, theta_b, query_r, pre_r,   thetaR, 257, 0 };
  pc.c[4] = { left,  phi_w,   phi_b,   key_l,   nullptr, phiTR,  256, 0 };
  pc.c[5] = { left,  g_w,     g_b,     nullptr, nullptr, gTR,    256, 1 };
  ra_proj6<<<1536, blk, 0, stream>>>(pc);

  ra_flash<<<512, blk, 0, stream>>>(thetaL, phiTL, gTL, thetaR, phiTR, gTR, pO, mla);
  ra_combine<<<16384, blk, 0, stream>>>(pO, mla, afterL, afterR,
                                        out + 8388608, out + 8404992);
  ra_up<<<1024, blk, 0, stream>>>(afterL, afterR, up_w, up_b, yL, yR);
  ra_stats<<<512, blk, 0, stream>>>(yL, yR, stL, stR);
  ra_fin<<<8192, blk, 0, stream>>>(left, right, yL, yR, stL, stR, bn_g, bn_b, out);

  (void)in_sizes; (void)n_in; (void)out_size; (void)ws_size;
}

// Round 6
// 337.684 us; speedup vs baseline: 1.2345x; 1.2345x over previous
//
#include <hip/hip_runtime.h>

// row_attention_maxindex on MI355X — R10 (resubmit; prior run was an infra
// failure, container never ran the kernel). MFMA projections:
// ra_flash reverted to R8 (best: 153us; R9's 32q/wave regressed).
// ra_proj6 (fp32 scalar FMA, ~41us VALU floor) -> ra_projm: 16x16x32 f16
// MFMA, 128pos x 128r blocks, x transposed to [pos][c] fp16 in LDS via 4x4
// register transpose, w staged [r][c] fp16. Operand-swap gives b64 stores
// for both output orientations. ra_up -> ra_upm: after stored fp16 (combine
// f2h) so A-frags load straight from global; w staged once; D[pos][co].

typedef unsigned short u16;
typedef unsigned int   u32;
typedef float        floatx4 __attribute__((ext_vector_type(4)));
typedef unsigned int uintx4  __attribute__((ext_vector_type(4)));
typedef unsigned int uintx2  __attribute__((ext_vector_type(2)));
typedef _Float16     half8   __attribute__((ext_vector_type(8)));
typedef __fp16       fp16x2  __attribute__((ext_vector_type(2)));

#define HW 4096
#define CB 256
#define RP 128
#define EPSF 1e-5f

static __device__ __forceinline__ u16 f2bf(float f) {
  u32 u = __float_as_uint(f);
  u32 r = u + 0x7FFFu + ((u >> 16) & 1u);   // RNE
  return (u16)(r >> 16);
}
static __device__ __forceinline__ float bf2f(u16 h) {
  return __uint_as_float(((u32)h) << 16);
}
static __device__ __forceinline__ u16 f2h(float f) {
  _Float16 h = (_Float16)f;                 // RNE
  return __builtin_bit_cast(u16, h);
}
static __device__ __forceinline__ float h2f(u16 h) {
  return (float)__builtin_bit_cast(_Float16, h);
}
static __device__ __forceinline__ half8 as_h8(uintx4 v) {
  return __builtin_bit_cast(half8, v);
}
static __device__ __forceinline__ u32 pkrtz(float a, float b) {
  fp16x2 h = __builtin_amdgcn_cvt_pkrtz(a, b);
  return __builtin_bit_cast(u32, h);
}
static __device__ __forceinline__ u32 pk2h(float a, float b) {  // RNE pair
  return (u32)f2h(a) | ((u32)f2h(b) << 16);
}
// Barrier with DS-visibility only: does NOT drain vmcnt.
static __device__ __forceinline__ void barrier_nodrain() {
  __builtin_amdgcn_sched_barrier(0);
  asm volatile("s_waitcnt lgkmcnt(0)" ::: "memory");
  __builtin_amdgcn_s_barrier();
  __builtin_amdgcn_sched_barrier(0);
}

union Pk4 { u16 u[4]; uintx2 v; };

// ---------------------------------------------------------------------------
// MFMA mega-projection: 6 projections, blockIdx>>7 selects config.
// Block = 128 pos x 128 r, 4 waves (wave owns 32 rows of D's M dim).
// Non-transposed (theta/phi): D[r][pos] = w.x  -> out[b][pos][r], b64 stores.
// Transposed (g):            D[pos][r] = xT.wT -> out[b][r][pos], b64 stores.
// Both read the SAME fragment patterns from x_lds[pos][c] / w_lds[r][c];
// only the A/B roles swap. K = 256 in 8 chunks of 32; fp16 inputs (RNE),
// fp32 MFMA accumulate; pre-channel (c=256) + bias + addend in epilogue.
// ---------------------------------------------------------------------------
struct ProjCfg {
  const float* x; const float* w; const float* bias;
  const float* add; const float* pre; u16* out;
  int wstride; int transposed;
};
struct ProjCfg6 { ProjCfg c[6]; };

#define XSTR 40   // u16 stride of [128][32] fp16 LDS tiles (80B: 16B-aligned rows)

__global__ __launch_bounds__(256) void ra_projm(ProjCfg6 cfg)
{
  __shared__ u16 x_lds[128 * XSTR];   // [pos][c32]
  __shared__ u16 w_lds[128 * XSTR];   // [r][c32]
  const ProjCfg C = cfg.c[blockIdx.x >> 7];
  const int inner = blockIdx.x & 127;       // b(4) x posb(32)
  const int b    = inner >> 5;
  const int pos0 = (inner & 31) * 128;
  const int tid  = threadIdx.x;
  const int wv   = tid >> 6;
  const int lane = tid & 63;
  const int ln16 = lane & 15;
  const int quad = lane >> 4;
  const int mbase = wv * 32;

  // staging indices
  const int xc0 = (tid & 7) * 4, xp0 = (tid >> 3) * 4;   // x: 4c x 4pos
  const int wrr = tid >> 1, wch = (tid & 1) * 16;        // w: 1r x 16c

  floatx4 acc[2][8];
  #pragma unroll
  for (int mt = 0; mt < 2; mt++)
    #pragma unroll
    for (int nt = 0; nt < 8; nt++) acc[mt][nt] = (floatx4)0.0f;

  #pragma unroll 1
  for (int cc = 0; cc < 8; ++cc) {
    // global loads -> regs (+cvt later)
    floatx4 xr[4];
    #pragma unroll
    for (int i = 0; i < 4; i++)
      xr[i] = *(const floatx4*)(C.x + (size_t)(b * CB + cc * 32 + xc0 + i) * HW + pos0 + xp0);
    float ww[16];
    {
      const float* wp = C.w + (size_t)wrr * C.wstride + cc * 32 + wch;
      #pragma unroll
      for (int i = 0; i < 16; i++) ww[i] = wp[i];   // scalar: stride may be odd (257)
    }
    __syncthreads();   // previous chunk's reads done
    // x transpose-write: 4 pos rows, each 4 c packed -> b64
    #pragma unroll
    for (int pp = 0; pp < 4; pp++) {
      uintx2 v;
      v[0] = pk2h(xr[0][pp], xr[1][pp]);
      v[1] = pk2h(xr[2][pp], xr[3][pp]);
      *(uintx2*)&x_lds[(xp0 + pp) * XSTR + xc0] = v;
    }
    // w write: 16 c in one row -> 2 b128
    {
      uintx4 v0, v1;
      v0[0] = pk2h(ww[0], ww[1]);  v0[1] = pk2h(ww[2], ww[3]);
      v0[2] = pk2h(ww[4], ww[5]);  v0[3] = pk2h(ww[6], ww[7]);
      v1[0] = pk2h(ww[8], ww[9]);  v1[1] = pk2h(ww[10], ww[11]);
      v1[2] = pk2h(ww[12], ww[13]); v1[3] = pk2h(ww[14], ww[15]);
      *(uintx4*)&w_lds[wrr * XSTR + wch]     = v0;
      *(uintx4*)&w_lds[wrr * XSTR + wch + 8] = v1;
    }
    __syncthreads();   // tile visible
    if (!C.transposed) {
      // A = w rows (wave-owned r), B = x rows (pos)
      half8 a0 = as_h8(*(const uintx4*)&w_lds[(mbase + ln16) * XSTR + quad * 8]);
      half8 a1 = as_h8(*(const uintx4*)&w_lds[(mbase + 16 + ln16) * XSTR + quad * 8]);
      #pragma unroll
      for (int nt = 0; nt < 8; nt++) {
        half8 bf = as_h8(*(const uintx4*)&x_lds[(nt * 16 + ln16) * XSTR + quad * 8]);
        acc[0][nt] = __builtin_amdgcn_mfma_f32_16x16x32_f16(a0, bf, acc[0][nt], 0, 0, 0);
        acc[1][nt] = __builtin_amdgcn_mfma_f32_16x16x32_f16(a1, bf, acc[1][nt], 0, 0, 0);
      }
    } else {
      // A = x rows (wave-owned pos), B = w rows (r)
      half8 a0 = as_h8(*(const uintx4*)&x_lds[(mbase + ln16) * XSTR + quad * 8]);
      half8 a1 = as_h8(*(const uintx4*)&x_lds[(mbase + 16 + ln16) * XSTR + quad * 8]);
      #pragma unroll
      for (int nt = 0; nt < 8; nt++) {
        half8 bf = as_h8(*(const uintx4*)&w_lds[(nt * 16 + ln16) * XSTR + quad * 8]);
        acc[0][nt] = __builtin_amdgcn_mfma_f32_16x16x32_f16(a0, bf, acc[0][nt], 0, 0, 0);
        acc[1][nt] = __builtin_amdgcn_mfma_f32_16x16x32_f16(a1, bf, acc[1][nt], 0, 0, 0);
      }
    }
  }

  // epilogue
  if (!C.transposed) {
    // D[r][pos]: lane holds r = mbase+mt*16+quad*4+rr, pos = pos0+nt*16+ln16
    #pragma unroll
    for (int mt = 0; mt < 2; mt++) {
      const int r0 = mbase + mt * 16 + quad * 4;
      floatx4 bi = *(const floatx4*)(C.bias + r0);
      float wc[4];
      if (C.pre) {
        #pragma unroll
        for (int rr = 0; rr < 4; rr++) wc[rr] = C.w[(size_t)(r0 + rr) * C.wstride + 256];
      }
      #pragma unroll
      for (int nt = 0; nt < 8; nt++) {
        const int pos = pos0 + nt * 16 + ln16;
        floatx4 v = acc[mt][nt];
        #pragma unroll
        for (int rr = 0; rr < 4; rr++) v[rr] += bi[rr];
        if (C.pre) {
          const float pv = C.pre[(size_t)b * HW + pos] * (1.f / 128.f);
          #pragma unroll
          for (int rr = 0; rr < 4; rr++) v[rr] += pv * wc[rr];
        }
        if (C.add) {
          #pragma unroll
          for (int rr = 0; rr < 4; rr++)
            v[rr] += C.add[(size_t)(b * RP + r0 + rr) * HW + pos];
        }
        Pk4 pk;
        #pragma unroll
        for (int rr = 0; rr < 4; rr++) pk.u[rr] = f2h(v[rr]);
        *(uintx2*)(C.out + (size_t)(b * HW + pos) * RP + r0) = pk.v;
      }
    }
  } else {
    // D[pos][r]: lane holds pos = pos0+mbase+mt*16+quad*4+rr, r = nt*16+ln16
    #pragma unroll
    for (int nt = 0; nt < 8; nt++) {
      const int r = nt * 16 + ln16;
      const float bs = C.bias[r];
      #pragma unroll
      for (int mt = 0; mt < 2; mt++) {
        const int pv = pos0 + mbase + mt * 16 + quad * 4;
        floatx4 v = acc[mt][nt];
        Pk4 pk;
        #pragma unroll
        for (int rr = 0; rr < 4; rr++) pk.u[rr] = f2h(v[rr] + bs);
        *(uintx2*)(C.out + (size_t)(b * RP + r) * HW + pv) = pk.v;
      }
    }
  }
}

// ---------------------------------------------------------------------------
// Flash attention partials (both sides, split-K=2), transposed-S form. (R8)
// ---------------------------------------------------------------------------
__global__ __launch_bounds__(256) void ra_flash(
    const u16* __restrict__ thetaL, const u16* __restrict__ phiTL,
    const u16* __restrict__ gTL,
    const u16* __restrict__ thetaR, const u16* __restrict__ phiTR,
    const u16* __restrict__ gTR,
    u16* __restrict__ pO, float* __restrict__ mla)
{
  __shared__ uintx4 phi_lds[16 * 65];   // [rchunk8 cb(16)][k(64)]
  __shared__ uintx4 g_lds[8 * 129];     // [kchunk8 kcb(8)][v(128)]
  __shared__ u16 P_lds[4][16 * 76];     // per-wave [q(16)][k(64)], stride 76

  const int tid  = threadIdx.x;
  const int bx   = blockIdx.x;
  const int side = bx >> 9;
  const int sbx  = bx & 511;
  const u16* __restrict__ theta = side ? thetaR : thetaL;
  const u16* __restrict__ phiT  = side ? phiTR  : phiTL;
  const u16* __restrict__ gT    = side ? gTR    : gTL;

  const int b    = sbx >> 7;
  const int rem  = sbx & 127;
  const int q0   = (rem >> 1) * 64;
  const int split= rem & 1;
  const int kbase= split * 2048;
  const int wv   = tid >> 6;
  const int lane = tid & 63;
  const int ln16 = lane & 15;
  const int quad = lane >> 4;

  uintx4 aq[4];
  {
    const uintx4* tr = (const uintx4*)(theta + (size_t)(b * HW + q0 + wv * 16 + ln16) * RP);
    #pragma unroll
    for (int c = 0; c < 4; c++) aq[c] = tr[c * 4 + quad];
  }

  floatx4 accO[8];
  #pragma unroll
  for (int v = 0; v < 8; v++) accO[v] = (floatx4)0.0f;
  float m_q = -3.0e38f, l_q = 0.f, aC_q = 0.f;

  const int sk  = tid >> 4, scb = tid & 15;  // phi staging
  const int gv_ = tid >> 3, gcb = tid & 7;   // g staging

  uintx4 sp[4], sg[4];
  #pragma unroll
  for (int i = 0; i < 4; i++) {
    sp[i] = *(const uintx4*)(phiT + (size_t)(b * HW + kbase + i * 16 + sk) * RP + scb * 8);
    sg[i] = *(const uintx4*)(gT + (size_t)(b * RP + i * 32 + gv_) * HW + kbase + gcb * 8);
  }

  #pragma unroll 1
  for (int j = 0; j < 32; j++) {
    #pragma unroll
    for (int i = 0; i < 4; i++) {
      phi_lds[scb * 65 + i * 16 + sk] = sp[i];
      g_lds[gcb * 129 + i * 32 + gv_] = sg[i];
    }
    if (j < 31) {
      const int k0n = kbase + (j + 1) * 64;
      #pragma unroll
      for (int i = 0; i < 4; i++) {
        sp[i] = *(const uintx4*)(phiT + (size_t)(b * HW + k0n + i * 16 + sk) * RP + scb * 8);
        sg[i] = *(const uintx4*)(gT + (size_t)(b * RP + i * 32 + gv_) * HW + k0n + gcb * 8);
      }
    }
    barrier_nodrain();

    floatx4 sf[4];
    #pragma unroll
    for (int s = 0; s < 4; s++) sf[s] = (floatx4)0.0f;
    __builtin_amdgcn_s_setprio(1);
    #pragma unroll
    for (int c = 0; c < 4; c++) {
      half8 bth = as_h8(aq[c]);
      #pragma unroll
      for (int s = 0; s < 4; s++) {
        uintx4 ap = phi_lds[(c * 4 + quad) * 65 + s * 16 + ln16];
        sf[s] = __builtin_amdgcn_mfma_f32_16x16x32_f16(as_h8(ap), bth, sf[s], 0, 0, 0);
      }
    }
    __builtin_amdgcn_s_setprio(0);

    float ms0 = fmaxf(fmaxf(sf[0][0], sf[0][1]), fmaxf(sf[0][2], sf[0][3]));
    float ms1 = fmaxf(fmaxf(sf[1][0], sf[1][1]), fmaxf(sf[1][2], sf[1][3]));
    float ms2 = fmaxf(fmaxf(sf[2][0], sf[2][1]), fmaxf(sf[2][2], sf[2][3]));
    float ms3 = fmaxf(fmaxf(sf[3][0], sf[3][1]), fmaxf(sf[3][2], sf[3][3]));
    float mx = fmaxf(fmaxf(ms0, ms1), fmaxf(ms2, ms3));
    mx = fmaxf(mx, __shfl_xor(mx, 16));
    mx = fmaxf(mx, __shfl_xor(mx, 32));
    if (__any(mx > m_q + 8.f)) {
      const float mnew  = fmaxf(m_q, mx);
      const float alpha = __expf(m_q - mnew);
      m_q = mnew;
      l_q *= alpha; aC_q *= alpha;
      #pragma unroll
      for (int v = 0; v < 8; v++) accO[v] *= alpha;
    }
    const float colbase = (float)((j * 64) & 127) + (float)(quad * 4);
    float ps = 0.f, pc = 0.f;
    #pragma unroll
    for (int s = 0; s < 4; s++) {
      float p0 = __expf(sf[s][0] - m_q);
      float p1 = __expf(sf[s][1] - m_q);
      float p2 = __expf(sf[s][2] - m_q);
      float p3 = __expf(sf[s][3] - m_q);
      ps += (p0 + p1) + (p2 + p3);
      const float cb = colbase + (float)(s * 16);
      pc += p0 * cb + p1 * (cb + 1.f) + p2 * (cb + 2.f) + p3 * (cb + 3.f);
      uintx2 pkv;
      pkv[0] = pkrtz(p0, p1);
      pkv[1] = pkrtz(p2, p3);
      *(uintx2*)&P_lds[wv][ln16 * 76 + s * 16 + quad * 4] = pkv;
    }
    ps += __shfl_xor(ps, 16); ps += __shfl_xor(ps, 32);
    pc += __shfl_xor(pc, 16); pc += __shfl_xor(pc, 32);
    l_q  += ps;
    aC_q += pc;

    half8 pb0 = as_h8(*(const uintx4*)&P_lds[wv][ln16 * 76 + quad * 8]);
    half8 pb1 = as_h8(*(const uintx4*)&P_lds[wv][ln16 * 76 + 32 + quad * 8]);
    __builtin_amdgcn_s_setprio(1);
    #pragma unroll
    for (int vt = 0; vt < 8; vt++) {
      uintx4 ag0 = g_lds[quad * 129 + vt * 16 + ln16];
      uintx4 ag1 = g_lds[(4 + quad) * 129 + vt * 16 + ln16];
      accO[vt] = __builtin_amdgcn_mfma_f32_16x16x32_f16(as_h8(ag0), pb0, accO[vt], 0, 0, 0);
      accO[vt] = __builtin_amdgcn_mfma_f32_16x16x32_f16(as_h8(ag1), pb1, accO[vt], 0, 0, 0);
    }
    __builtin_amdgcn_s_setprio(0);
    barrier_nodrain();
  }

  const int q = q0 + wv * 16 + ln16;
  const size_t p = (size_t)side * 32768 + (size_t)split * 16384 + b * HW + q;
  u16* orow = pO + p * RP;
  const float invl = 1.f / l_q;
  #pragma unroll
  for (int vt = 0; vt < 8; vt++) {
    uintx2 pkv;
    pkv[0] = pkrtz(accO[vt][0] * invl, accO[vt][1] * invl);
    pkv[1] = pkrtz(accO[vt][2] * invl, accO[vt][3] * invl);
    *(uintx2*)(orow + vt * 16 + quad * 4) = pkv;
  }
  if (quad == 0) {
    floatx4 m4; m4[0] = m_q; m4[1] = l_q; m4[2] = aC_q; m4[3] = 0.f;
    *(floatx4*)(mla + p * 4) = m4;
  }
}

// ---------------------------------------------------------------------------
// Combine split-K partials: after (FP16 now, feeds MFMA up) + index (fp32).
// ---------------------------------------------------------------------------
__global__ __launch_bounds__(256) void ra_combine(
    const u16* __restrict__ pO, const float* __restrict__ mla,
    u16* __restrict__ afterL, u16* __restrict__ afterR,
    float* __restrict__ idxL, float* __restrict__ idxR)
{
  const int t = threadIdx.x;
  const int pp = blockIdx.x * 2 + (t >> 7);
  const int side = pp >> 14;
  const int p = pp & 16383;
  const int v = t & 127;
  const size_t base = (size_t)side * 32768;
  const floatx4 A  = *(const floatx4*)(mla + (base + p) * 4);
  const floatx4 Bv = *(const floatx4*)(mla + (base + 16384 + p) * 4);
  const float M  = fmaxf(A[0], Bv[0]);
  const float w0 = __expf(A[0] - M), w1 = __expf(Bv[0] - M);
  const float s0 = w0 * A[1], s1 = w1 * Bv[1];     // w * l
  const float inv = 1.0f / (s0 + s1);
  const float a0 = h2f(pO[(base + p) * RP + v]);
  const float a1 = h2f(pO[(base + 16384 + p) * RP + v]);
  u16* after = side ? afterR : afterL;
  after[(size_t)p * RP + v] = f2h((s0 * a0 + s1 * a1) * inv);   // fp16
  if (v == 0) {
    float* idx = side ? idxR : idxL;
    idx[p] = (float)(p & 127) - (w0 * A[2] + w1 * Bv[2]) * inv;
  }
}

// ---------------------------------------------------------------------------
// MFMA up-projection: y[b,co,pos] = after[b,pos,:]·up_w[co,:] + up_b.
// Block = 128 pos x 128 co (hc selects co-half); wave owns 32 pos.
// A = after (fp16, [pos][r] == A-fragment layout -> direct global b128).
// B = up_w fp16 staged once to LDS [co][r]. D[pos][co] -> b64 stores.
// ---------------------------------------------------------------------------
#define WSTR 136   // u16 stride (272B, 16B-aligned rows)

__global__ __launch_bounds__(256) void ra_upm(
    const u16* __restrict__ afterL, const u16* __restrict__ afterR,
    const float* __restrict__ w, const float* __restrict__ bias,
    u16* __restrict__ yL, u16* __restrict__ yR)
{
  __shared__ u16 w_lds[128 * WSTR];   // [co][r]
  const int tid  = threadIdx.x;
  const int bx   = blockIdx.x;
  const int side = bx >> 8;
  const int sbx  = bx & 255;
  const u16* __restrict__ after = side ? afterR : afterL;
  u16* __restrict__ y = side ? yR : yL;
  const int b    = sbx >> 6;
  const int pos0 = ((sbx >> 1) & 31) * 128;
  const int hc   = sbx & 1;
  const int wv   = tid >> 6;
  const int lane = tid & 63;
  const int ln16 = lane & 15;
  const int quad = lane >> 4;

  // stage w half [128 co][128 r] fp32 -> fp16 (one time)
  {
    const int co = tid >> 1, rh = (tid & 1) * 64;
    const float* wp = w + (size_t)(hc * 128 + co) * RP + rh;
    #pragma unroll
    for (int i = 0; i < 8; i++) {
      floatx4 f0 = *(const floatx4*)(wp + i * 8);
      floatx4 f1 = *(const floatx4*)(wp + i * 8 + 4);
      uintx4 v;
      v[0] = pk2h(f0[0], f0[1]); v[1] = pk2h(f0[2], f0[3]);
      v[2] = pk2h(f1[0], f1[1]); v[3] = pk2h(f1[2], f1[3]);
      *(uintx4*)&w_lds[co * WSTR + rh + i * 8] = v;
    }
  }
  __syncthreads();

  floatx4 acc[2][8];
  #pragma unroll
  for (int mt = 0; mt < 2; mt++)
    #pragma unroll
    for (int nt = 0; nt < 8; nt++) acc[mt][nt] = (floatx4)0.0f;

  #pragma unroll
  for (int kk = 0; kk < 4; kk++) {
    half8 a[2];
    #pragma unroll
    for (int mt = 0; mt < 2; mt++)
      a[mt] = as_h8(*(const uintx4*)(after +
          (size_t)(b * HW + pos0 + wv * 32 + mt * 16 + ln16) * RP + kk * 32 + quad * 8));
    #pragma unroll
    for (int nt = 0; nt < 8; nt++) {
      half8 bf = as_h8(*(const uintx4*)&w_lds[(nt * 16 + ln16) * WSTR + kk * 32 + quad * 8]);
      acc[0][nt] = __builtin_amdgcn_mfma_f32_16x16x32_f16(a[0], bf, acc[0][nt], 0, 0, 0);
      acc[1][nt] = __builtin_amdgcn_mfma_f32_16x16x32_f16(a[1], bf, acc[1][nt], 0, 0, 0);
    }
  }

  // epilogue: D[pos][co]: lane holds pos = pos0+wv*32+mt*16+quad*4+rr, co = nt*16+ln16
  #pragma unroll
  for (int nt = 0; nt < 8; nt++) {
    const int co = hc * 128 + nt * 16 + ln16;
    const float bs = bias[co];
    #pragma unroll
    for (int mt = 0; mt < 2; mt++) {
      const int pv = pos0 + wv * 32 + mt * 16 + quad * 4;
      floatx4 v = acc[mt][nt];
      Pk4 pk;
      #pragma unroll
      for (int rr = 0; rr < 4; rr++) pk.u[rr] = f2bf(v[rr] + bs);
      *(uintx2*)(y + (size_t)(b * CB + co) * HW + pv) = pk.v;
    }
  }
}

// ---------------------------------------------------------------------------
// Per-channel batch stats (both sides) over (B, HW): mean and rstd.
// ---------------------------------------------------------------------------
__global__ __launch_bounds__(256) void ra_stats(
    const u16* __restrict__ yL, const u16* __restrict__ yR,
    float* __restrict__ stL, float* __restrict__ stR)
{
  const int side = blockIdx.x >> 8;
  const int c = blockIdx.x & 255;
  const u16* __restrict__ y = side ? yR : yL;
  float* __restrict__ stats = side ? stR : stL;
  const int tid = threadIdx.x;
  float s = 0.f, sq = 0.f;
  for (int b = 0; b < 4; b++) {
    const uintx4* row = (const uintx4*)(y + (size_t)(b * CB + c) * HW);
    #pragma unroll
    for (int t = 0; t < 2; t++) {
      uintx4 rv = row[tid + t * 256];
      #pragma unroll
      for (int k = 0; k < 4; k++) {
        float a0 = bf2f((u16)(rv[k] & 0xffffu));
        float a1 = bf2f((u16)(rv[k] >> 16));
        s += a0 + a1; sq += a0 * a0 + a1 * a1;
      }
    }
  }
  #pragma unroll
  for (int m = 1; m < 64; m <<= 1) { s += __shfl_xor(s, m); sq += __shfl_xor(sq, m); }
  __shared__ float red[8];
  const int wv = tid >> 6;
  if ((tid & 63) == 0) { red[wv * 2] = s; red[wv * 2 + 1] = sq; }
  __syncthreads();
  if (tid == 0) {
    s  = red[0] + red[2] + red[4] + red[6];
    sq = red[1] + red[3] + red[5] + red[7];
    const float mean = s * (1.f / 16384.f);
    const float var  = sq * (1.f / 16384.f) - mean * mean;
    stats[2 * c]     = mean;
    stats[2 * c + 1] = rsqrtf(var + EPSF);
  }
}

// ---------------------------------------------------------------------------
// out = x + gamma*(y - mean)*rstd + beta  (both sides, float4)
// ---------------------------------------------------------------------------
__global__ __launch_bounds__(256) void ra_fin(
    const float* __restrict__ left, const float* __restrict__ right,
    const u16* __restrict__ yL, const u16* __restrict__ yR,
    const float* __restrict__ stL, const float* __restrict__ stR,
    const float* __restrict__ gamma, const float* __restrict__ beta,
    float* __restrict__ out)
{
  const size_t e = (size_t)blockIdx.x * 256 + threadIdx.x;  // global float4 idx
  const int side = (int)(e >> 20);
  const size_t e4 = e & 1048575;
  const int c = (int)((e4 >> 10) & 255);
  const float* x = side ? right : left;
  const u16* y = side ? yR : yL;
  const float* stats = side ? stR : stL;
  const float mean = stats[2 * c], rstd = stats[2 * c + 1];
  const float ga = gamma[c], be = beta[c];
  floatx4 xv = ((const floatx4*)x)[e4];
  uintx2 yv = ((const uintx2*)y)[e4];
  float f0 = bf2f((u16)(yv[0] & 0xffffu));
  float f1 = bf2f((u16)(yv[0] >> 16));
  float f2 = bf2f((u16)(yv[1] & 0xffffu));
  float f3 = bf2f((u16)(yv[1] >> 16));
  floatx4 o;
  o[0] = xv[0] + ga * ((f0 - mean) * rstd) + be;
  o[1] = xv[1] + ga * ((f1 - mean) * rstd) + be;
  o[2] = xv[2] + ga * ((f2 - mean) * rstd) + be;
  o[3] = xv[3] + ga * ((f3 - mean) * rstd) + be;
  ((floatx4*)out)[(size_t)side * 1048576 + e4] = o;
}

// ---------------------------------------------------------------------------
extern "C" void kernel_launch(void* const* d_in, const int* in_sizes, int n_in,
                              void* d_out, int out_size, void* d_ws, size_t ws_size,
                              hipStream_t stream)
{
  const float* left    = (const float*)d_in[0];
  const float* right   = (const float*)d_in[1];
  const float* pre_l   = (const float*)d_in[2];
  const float* pre_r   = (const float*)d_in[3];
  const float* query_l = (const float*)d_in[4];
  const float* key_l   = (const float*)d_in[5];
  const float* query_r = (const float*)d_in[6];
  const float* key_r   = (const float*)d_in[7];
  const float* theta_w = (const float*)d_in[8];
  const float* theta_b = (const float*)d_in[9];
  const float* phi_w   = (const float*)d_in[10];
  const float* phi_b   = (const float*)d_in[11];
  const float* g_w     = (const float*)d_in[12];
  const float* g_b     = (const float*)d_in[13];
  const float* up_w    = (const float*)d_in[14];
  const float* up_b    = (const float*)d_in[15];
  const float* bn_g    = (const float*)d_in[16];
  const float* bn_b    = (const float*)d_in[17];
  float* out = (float*)d_out;

  char* ws = (char*)d_ws;
  const size_t SZ = (size_t)4 * HW * RP * 2;  // 4 MiB (fp16 [4][4096][128])
  u16* thetaL = (u16*)(ws);
  u16* phiTL  = (u16*)(ws + 1 * SZ);
  u16* gTL    = (u16*)(ws + 2 * SZ);
  u16* thetaR = (u16*)(ws + 3 * SZ);
  u16* phiTR  = (u16*)(ws + 4 * SZ);
  u16* gTR    = (u16*)(ws + 5 * SZ);
  u16* afterL = (u16*)(ws + 6 * SZ);
  u16* afterR = (u16*)(ws + 7 * SZ);
  u16* pO     = (u16*)(ws + 8 * SZ);    // 16 MiB (2 sides x 2 splits), aliased w/ y
  u16* yL     = (u16*)(ws + 8 * SZ);    // 8 MiB (written after pO is consumed)
  u16* yR     = (u16*)(ws + 10 * SZ);   // 8 MiB
  float* stL  = (float*)(ws + 12 * SZ);
  float* stR  = (float*)(ws + 12 * SZ + 2048);
  float* mla  = (float*)(ws + 12 * SZ + 8192);  // 1 MiB (65536 x 4 fp32)

  dim3 blk(256);
  // side L: x_q=left, x_kv=right, query_l, key_r; side R mirrored.
  ProjCfg6 pc;
  pc.c[0] = { left,  theta_w, theta_b, query_l, pre_l,   thetaL, 257, 0 };
  pc.c[1] = { right, phi_w,   phi_b,   key_r,   nullptr, phiTL,  256, 0 };
  pc.c[2] = { right, g_w,     g_b,     nullptr, nullptr, gTL,    256, 1 };
  pc.c[3] = { right, theta_w, theta_b, query_r, pre_r,   thetaR, 257, 0 };
  pc.c[4] = { left,  phi_w,   phi_b,   key_l,   nullptr, phiTR,  256, 0 };
  pc.c[5] = { left,  g_w,     g_b,     nullptr, nullptr, gTR,    256, 1 };
  ra_projm<<<768, blk, 0, stream>>>(pc);

  ra_flash<<<1024, blk, 0, stream>>>(thetaL, phiTL, gTL, thetaR, phiTR, gTR, pO, mla);
  ra_combine<<<16384, blk, 0, stream>>>(pO, mla, afterL, afterR,
                                        out + 8388608, out + 8404992);
  ra_upm<<<512, blk, 0, stream>>>(afterL, afterR, up_w, up_b, yL, yR);
  ra_stats<<<512, blk, 0, stream>>>(yL, yR, stL, stR);
  ra_fin<<<8192, blk, 0, stream>>>(left, right, yL, yR, stL, stR, bn_g, bn_b, out);

  (void)in_sizes; (void)n_in; (void)out_size; (void)ws_size;
}

// Round 7
// 318.216 us; speedup vs baseline: 1.3100x; 1.0612x over previous
//
#include <hip/hip_runtime.h>

// row_attention_maxindex on MI355X — R11: no-split flash + MFMA-softmax.
// (1) split-K removed: 512 blocks x 64 K-iters; flash writes normalized
//     after (fp16) + idx directly; ra_combine + pO/mla eliminated.
// (2) l (=Σp) and aC (=Σp·col) accumulate via PV MFMA: a 2-row colones
//     A-fragment (row0 = k-in-tile, row1 = 1) in registers; even/odd j
//     go to separate acc tiles so col = (j&1)*64 + kk reconstructs as
//     aC = Σp·kk + 64·l_odd. Removes ps/pc VALU chain + 4 shuffles/iter.
// ra_projm / ra_upm / ra_stats / ra_fin unchanged from R10.

typedef unsigned short u16;
typedef unsigned int   u32;
typedef float        floatx4 __attribute__((ext_vector_type(4)));
typedef unsigned int uintx4  __attribute__((ext_vector_type(4)));
typedef unsigned int uintx2  __attribute__((ext_vector_type(2)));
typedef _Float16     half8   __attribute__((ext_vector_type(8)));
typedef __fp16       fp16x2  __attribute__((ext_vector_type(2)));

#define HW 4096
#define CB 256
#define RP 128
#define EPSF 1e-5f

static __device__ __forceinline__ u16 f2bf(float f) {
  u32 u = __float_as_uint(f);
  u32 r = u + 0x7FFFu + ((u >> 16) & 1u);   // RNE
  return (u16)(r >> 16);
}
static __device__ __forceinline__ float bf2f(u16 h) {
  return __uint_as_float(((u32)h) << 16);
}
static __device__ __forceinline__ u16 f2h(float f) {
  _Float16 h = (_Float16)f;                 // RNE
  return __builtin_bit_cast(u16, h);
}
static __device__ __forceinline__ float h2f(u16 h) {
  return (float)__builtin_bit_cast(_Float16, h);
}
static __device__ __forceinline__ half8 as_h8(uintx4 v) {
  return __builtin_bit_cast(half8, v);
}
static __device__ __forceinline__ u32 pkrtz(float a, float b) {
  fp16x2 h = __builtin_amdgcn_cvt_pkrtz(a, b);
  return __builtin_bit_cast(u32, h);
}
static __device__ __forceinline__ u32 pk2h(float a, float b) {  // RNE pair
  return (u32)f2h(a) | ((u32)f2h(b) << 16);
}
// Barrier with DS-visibility only: does NOT drain vmcnt.
static __device__ __forceinline__ void barrier_nodrain() {
  __builtin_amdgcn_sched_barrier(0);
  asm volatile("s_waitcnt lgkmcnt(0)" ::: "memory");
  __builtin_amdgcn_s_barrier();
  __builtin_amdgcn_sched_barrier(0);
}

union Pk4 { u16 u[4]; uintx2 v; };

// ---------------------------------------------------------------------------
// MFMA mega-projection: 6 projections, blockIdx>>7 selects config. (R10)
// ---------------------------------------------------------------------------
struct ProjCfg {
  const float* x; const float* w; const float* bias;
  const float* add; const float* pre; u16* out;
  int wstride; int transposed;
};
struct ProjCfg6 { ProjCfg c[6]; };

#define XSTR 40   // u16 stride of [128][32] fp16 LDS tiles

__global__ __launch_bounds__(256) void ra_projm(ProjCfg6 cfg)
{
  __shared__ u16 x_lds[128 * XSTR];   // [pos][c32]
  __shared__ u16 w_lds[128 * XSTR];   // [r][c32]
  const ProjCfg C = cfg.c[blockIdx.x >> 7];
  const int inner = blockIdx.x & 127;       // b(4) x posb(32)
  const int b    = inner >> 5;
  const int pos0 = (inner & 31) * 128;
  const int tid  = threadIdx.x;
  const int wv   = tid >> 6;
  const int lane = tid & 63;
  const int ln16 = lane & 15;
  const int quad = lane >> 4;
  const int mbase = wv * 32;

  const int xc0 = (tid & 7) * 4, xp0 = (tid >> 3) * 4;   // x: 4c x 4pos
  const int wrr = tid >> 1, wch = (tid & 1) * 16;        // w: 1r x 16c

  floatx4 acc[2][8];
  #pragma unroll
  for (int mt = 0; mt < 2; mt++)
    #pragma unroll
    for (int nt = 0; nt < 8; nt++) acc[mt][nt] = (floatx4)0.0f;

  #pragma unroll 1
  for (int cc = 0; cc < 8; ++cc) {
    floatx4 xr[4];
    #pragma unroll
    for (int i = 0; i < 4; i++)
      xr[i] = *(const floatx4*)(C.x + (size_t)(b * CB + cc * 32 + xc0 + i) * HW + pos0 + xp0);
    float ww[16];
    {
      const float* wp = C.w + (size_t)wrr * C.wstride + cc * 32 + wch;
      #pragma unroll
      for (int i = 0; i < 16; i++) ww[i] = wp[i];   // scalar: stride may be odd (257)
    }
    __syncthreads();   // previous chunk's reads done
    #pragma unroll
    for (int pp = 0; pp < 4; pp++) {
      uintx2 v;
      v[0] = pk2h(xr[0][pp], xr[1][pp]);
      v[1] = pk2h(xr[2][pp], xr[3][pp]);
      *(uintx2*)&x_lds[(xp0 + pp) * XSTR + xc0] = v;
    }
    {
      uintx4 v0, v1;
      v0[0] = pk2h(ww[0], ww[1]);  v0[1] = pk2h(ww[2], ww[3]);
      v0[2] = pk2h(ww[4], ww[5]);  v0[3] = pk2h(ww[6], ww[7]);
      v1[0] = pk2h(ww[8], ww[9]);  v1[1] = pk2h(ww[10], ww[11]);
      v1[2] = pk2h(ww[12], ww[13]); v1[3] = pk2h(ww[14], ww[15]);
      *(uintx4*)&w_lds[wrr * XSTR + wch]     = v0;
      *(uintx4*)&w_lds[wrr * XSTR + wch + 8] = v1;
    }
    __syncthreads();   // tile visible
    if (!C.transposed) {
      half8 a0 = as_h8(*(const uintx4*)&w_lds[(mbase + ln16) * XSTR + quad * 8]);
      half8 a1 = as_h8(*(const uintx4*)&w_lds[(mbase + 16 + ln16) * XSTR + quad * 8]);
      #pragma unroll
      for (int nt = 0; nt < 8; nt++) {
        half8 bf = as_h8(*(const uintx4*)&x_lds[(nt * 16 + ln16) * XSTR + quad * 8]);
        acc[0][nt] = __builtin_amdgcn_mfma_f32_16x16x32_f16(a0, bf, acc[0][nt], 0, 0, 0);
        acc[1][nt] = __builtin_amdgcn_mfma_f32_16x16x32_f16(a1, bf, acc[1][nt], 0, 0, 0);
      }
    } else {
      half8 a0 = as_h8(*(const uintx4*)&x_lds[(mbase + ln16) * XSTR + quad * 8]);
      half8 a1 = as_h8(*(const uintx4*)&x_lds[(mbase + 16 + ln16) * XSTR + quad * 8]);
      #pragma unroll
      for (int nt = 0; nt < 8; nt++) {
        half8 bf = as_h8(*(const uintx4*)&w_lds[(nt * 16 + ln16) * XSTR + quad * 8]);
        acc[0][nt] = __builtin_amdgcn_mfma_f32_16x16x32_f16(a0, bf, acc[0][nt], 0, 0, 0);
        acc[1][nt] = __builtin_amdgcn_mfma_f32_16x16x32_f16(a1, bf, acc[1][nt], 0, 0, 0);
      }
    }
  }

  if (!C.transposed) {
    #pragma unroll
    for (int mt = 0; mt < 2; mt++) {
      const int r0 = mbase + mt * 16 + quad * 4;
      floatx4 bi = *(const floatx4*)(C.bias + r0);
      float wc[4];
      if (C.pre) {
        #pragma unroll
        for (int rr = 0; rr < 4; rr++) wc[rr] = C.w[(size_t)(r0 + rr) * C.wstride + 256];
      }
      #pragma unroll
      for (int nt = 0; nt < 8; nt++) {
        const int pos = pos0 + nt * 16 + ln16;
        floatx4 v = acc[mt][nt];
        #pragma unroll
        for (int rr = 0; rr < 4; rr++) v[rr] += bi[rr];
        if (C.pre) {
          const float pv = C.pre[(size_t)b * HW + pos] * (1.f / 128.f);
          #pragma unroll
          for (int rr = 0; rr < 4; rr++) v[rr] += pv * wc[rr];
        }
        if (C.add) {
          #pragma unroll
          for (int rr = 0; rr < 4; rr++)
            v[rr] += C.add[(size_t)(b * RP + r0 + rr) * HW + pos];
        }
        Pk4 pk;
        #pragma unroll
        for (int rr = 0; rr < 4; rr++) pk.u[rr] = f2h(v[rr]);
        *(uintx2*)(C.out + (size_t)(b * HW + pos) * RP + r0) = pk.v;
      }
    }
  } else {
    #pragma unroll
    for (int nt = 0; nt < 8; nt++) {
      const int r = nt * 16 + ln16;
      const float bs = C.bias[r];
      #pragma unroll
      for (int mt = 0; mt < 2; mt++) {
        const int pv = pos0 + mbase + mt * 16 + quad * 4;
        floatx4 v = acc[mt][nt];
        Pk4 pk;
        #pragma unroll
        for (int rr = 0; rr < 4; rr++) pk.u[rr] = f2h(v[rr] + bs);
        *(uintx2*)(C.out + (size_t)(b * RP + r) * HW + pv) = pk.v;
      }
    }
  }
}

// ---------------------------------------------------------------------------
// Flash attention, NO split-K: block = (side, b, 64 q), 64 K-tiles of 64.
// l/aC accumulate via PV MFMA colones fragment (even/odd j separated).
// Writes normalized after (fp16) + idx directly.
// ---------------------------------------------------------------------------
__global__ __launch_bounds__(256) void ra_flash(
    const u16* __restrict__ thetaL, const u16* __restrict__ phiTL,
    const u16* __restrict__ gTL,
    const u16* __restrict__ thetaR, const u16* __restrict__ phiTR,
    const u16* __restrict__ gTR,
    u16* __restrict__ afterL, u16* __restrict__ afterR,
    float* __restrict__ idxL, float* __restrict__ idxR)
{
  __shared__ uintx4 phi_lds[16 * 65];   // [rchunk8 cb(16)][k(64)]
  __shared__ uintx4 g_lds[8 * 129];     // [kchunk8 kcb(8)][v(128)]
  __shared__ u16 P_lds[4][16 * 76];     // per-wave [q(16)][k(64)], stride 76

  const int tid  = threadIdx.x;
  const int bx   = blockIdx.x;
  const int side = bx >> 8;
  const int sbx  = bx & 255;
  const u16* __restrict__ theta = side ? thetaR : thetaL;
  const u16* __restrict__ phiT  = side ? phiTR  : phiTL;
  const u16* __restrict__ gT    = side ? gTR    : gTL;

  const int b    = sbx >> 6;
  const int q0   = (sbx & 63) * 64;
  const int wv   = tid >> 6;
  const int lane = tid & 63;
  const int ln16 = lane & 15;
  const int quad = lane >> 4;

  uintx4 aq[4];
  {
    const uintx4* tr = (const uintx4*)(theta + (size_t)(b * HW + q0 + wv * 16 + ln16) * RP);
    #pragma unroll
    for (int c = 0; c < 4; c++) aq[c] = tr[c * 4 + quad];
  }

  // colones A-fragment: row0 = k-in-tile (0..63), row1 = 1, rows 2..15 = 0.
  // A layout: lane(ln16,quad) holds A[m=ln16][k=half*32+quad*8+i].
  half8 cf0, cf1;
  {
    #pragma unroll
    for (int i = 0; i < 8; i++) {
      float c0 = (ln16 == 0) ? (float)(quad * 8 + i)      : (ln16 == 1 ? 1.f : 0.f);
      float c1 = (ln16 == 0) ? (float)(32 + quad * 8 + i) : (ln16 == 1 ? 1.f : 0.f);
      cf0[i] = (_Float16)c0;
      cf1[i] = (_Float16)c1;
    }
  }

  floatx4 accO[8];
  #pragma unroll
  for (int v = 0; v < 8; v++) accO[v] = (floatx4)0.0f;
  floatx4 accE  = (floatx4)0.0f;   // even-j: [0]=Σp·kk, [1]=Σp (rows 0,1 @quad0)
  floatx4 accEo = (floatx4)0.0f;   // odd-j
  float m_q = -3.0e38f;

  const int sk  = tid >> 4, scb = tid & 15;  // phi staging
  const int gv_ = tid >> 3, gcb = tid & 7;   // g staging

  uintx4 sp[4], sg[4];
  #pragma unroll
  for (int i = 0; i < 4; i++) {
    sp[i] = *(const uintx4*)(phiT + (size_t)(b * HW + i * 16 + sk) * RP + scb * 8);
    sg[i] = *(const uintx4*)(gT + (size_t)(b * RP + i * 32 + gv_) * HW + gcb * 8);
  }

  #pragma unroll 1
  for (int j = 0; j < 64; j++) {
    #pragma unroll
    for (int i = 0; i < 4; i++) {
      phi_lds[scb * 65 + i * 16 + sk] = sp[i];
      g_lds[gcb * 129 + i * 32 + gv_] = sg[i];
    }
    if (j < 63) {
      const int k0n = (j + 1) * 64;
      #pragma unroll
      for (int i = 0; i < 4; i++) {
        sp[i] = *(const uintx4*)(phiT + (size_t)(b * HW + k0n + i * 16 + sk) * RP + scb * 8);
        sg[i] = *(const uintx4*)(gT + (size_t)(b * RP + i * 32 + gv_) * HW + k0n + gcb * 8);
      }
    }
    barrier_nodrain();

    floatx4 sf[4];
    #pragma unroll
    for (int s = 0; s < 4; s++) sf[s] = (floatx4)0.0f;
    __builtin_amdgcn_s_setprio(1);
    #pragma unroll
    for (int c = 0; c < 4; c++) {
      half8 bth = as_h8(aq[c]);
      #pragma unroll
      for (int s = 0; s < 4; s++) {
        uintx4 ap = phi_lds[(c * 4 + quad) * 65 + s * 16 + ln16];
        sf[s] = __builtin_amdgcn_mfma_f32_16x16x32_f16(as_h8(ap), bth, sf[s], 0, 0, 0);
      }
    }
    __builtin_amdgcn_s_setprio(0);

    float ms0 = fmaxf(fmaxf(sf[0][0], sf[0][1]), fmaxf(sf[0][2], sf[0][3]));
    float ms1 = fmaxf(fmaxf(sf[1][0], sf[1][1]), fmaxf(sf[1][2], sf[1][3]));
    float ms2 = fmaxf(fmaxf(sf[2][0], sf[2][1]), fmaxf(sf[2][2], sf[2][3]));
    float ms3 = fmaxf(fmaxf(sf[3][0], sf[3][1]), fmaxf(sf[3][2], sf[3][3]));
    float mx = fmaxf(fmaxf(ms0, ms1), fmaxf(ms2, ms3));
    mx = fmaxf(mx, __shfl_xor(mx, 16));
    mx = fmaxf(mx, __shfl_xor(mx, 32));
    if (__any(mx > m_q + 8.f)) {       // wave-uniform, rare in steady state
      const float mnew  = fmaxf(m_q, mx);
      const float alpha = __expf(m_q - mnew);
      m_q = mnew;
      accE *= alpha; accEo *= alpha;
      #pragma unroll
      for (int v = 0; v < 8; v++) accO[v] *= alpha;
    }
    #pragma unroll
    for (int s = 0; s < 4; s++) {
      float p0 = __expf(sf[s][0] - m_q);
      float p1 = __expf(sf[s][1] - m_q);
      float p2 = __expf(sf[s][2] - m_q);
      float p3 = __expf(sf[s][3] - m_q);
      uintx2 pkv;
      pkv[0] = pkrtz(p0, p1);
      pkv[1] = pkrtz(p2, p3);
      *(uintx2*)&P_lds[wv][ln16 * 76 + s * 16 + quad * 4] = pkv;
    }

    // no barrier: P_lds is wave-private; DS ops in-order per wave.
    half8 pb0 = as_h8(*(const uintx4*)&P_lds[wv][ln16 * 76 + quad * 8]);
    half8 pb1 = as_h8(*(const uintx4*)&P_lds[wv][ln16 * 76 + 32 + quad * 8]);
    __builtin_amdgcn_s_setprio(1);
    #pragma unroll
    for (int vt = 0; vt < 8; vt++) {
      uintx4 ag0 = g_lds[quad * 129 + vt * 16 + ln16];
      uintx4 ag1 = g_lds[(4 + quad) * 129 + vt * 16 + ln16];
      accO[vt] = __builtin_amdgcn_mfma_f32_16x16x32_f16(as_h8(ag0), pb0, accO[vt], 0, 0, 0);
      accO[vt] = __builtin_amdgcn_mfma_f32_16x16x32_f16(as_h8(ag1), pb1, accO[vt], 0, 0, 0);
    }
    if (j & 1) {
      accEo = __builtin_amdgcn_mfma_f32_16x16x32_f16(cf0, pb0, accEo, 0, 0, 0);
      accEo = __builtin_amdgcn_mfma_f32_16x16x32_f16(cf1, pb1, accEo, 0, 0, 0);
    } else {
      accE  = __builtin_amdgcn_mfma_f32_16x16x32_f16(cf0, pb0, accE, 0, 0, 0);
      accE  = __builtin_amdgcn_mfma_f32_16x16x32_f16(cf1, pb1, accE, 0, 0, 0);
    }
    __builtin_amdgcn_s_setprio(0);
    barrier_nodrain();
  }

  // epilogue: l = Σp (all j), aC = Σp·kk + 64·Σp(odd j); both live in
  // quad0 lanes (rows 0,1); broadcast to the other quads via shfl.
  const float l0 = accE[1] + accEo[1];
  const float a0 = accE[0] + accEo[0] + 64.f * accEo[1];
  const float l_all  = __shfl(l0, ln16);
  const float aC_all = __shfl(a0, ln16);

  const int q = q0 + wv * 16 + ln16;
  const size_t p = (size_t)b * HW + q;
  u16* after = side ? afterR : afterL;
  u16* orow = after + p * RP;
  const float invl = 1.f / l_all;
  #pragma unroll
  for (int vt = 0; vt < 8; vt++) {
    uintx2 pkv;
    pkv[0] = pkrtz(accO[vt][0] * invl, accO[vt][1] * invl);
    pkv[1] = pkrtz(accO[vt][2] * invl, accO[vt][3] * invl);
    *(uintx2*)(orow + vt * 16 + quad * 4) = pkv;
  }
  if (quad == 0) {
    float* idx = side ? idxR : idxL;
    idx[p] = (float)(q & 127) - aC_all * invl;
  }
}

// ---------------------------------------------------------------------------
// MFMA up-projection: y[b,co,pos] = after[b,pos,:]·up_w[co,:] + up_b. (R10)
// ---------------------------------------------------------------------------
#define WSTR 136   // u16 stride (272B, 16B-aligned rows)

__global__ __launch_bounds__(256) void ra_upm(
    const u16* __restrict__ afterL, const u16* __restrict__ afterR,
    const float* __restrict__ w, const float* __restrict__ bias,
    u16* __restrict__ yL, u16* __restrict__ yR)
{
  __shared__ u16 w_lds[128 * WSTR];   // [co][r]
  const int tid  = threadIdx.x;
  const int bx   = blockIdx.x;
  const int side = bx >> 8;
  const int sbx  = bx & 255;
  const u16* __restrict__ after = side ? afterR : afterL;
  u16* __restrict__ y = side ? yR : yL;
  const int b    = sbx >> 6;
  const int pos0 = ((sbx >> 1) & 31) * 128;
  const int hc   = sbx & 1;
  const int wv   = tid >> 6;
  const int lane = tid & 63;
  const int ln16 = lane & 15;
  const int quad = lane >> 4;

  {
    const int co = tid >> 1, rh = (tid & 1) * 64;
    const float* wp = w + (size_t)(hc * 128 + co) * RP + rh;
    #pragma unroll
    for (int i = 0; i < 8; i++) {
      floatx4 f0 = *(const floatx4*)(wp + i * 8);
      floatx4 f1 = *(const floatx4*)(wp + i * 8 + 4);
      uintx4 v;
      v[0] = pk2h(f0[0], f0[1]); v[1] = pk2h(f0[2], f0[3]);
      v[2] = pk2h(f1[0], f1[1]); v[3] = pk2h(f1[2], f1[3]);
      *(uintx4*)&w_lds[co * WSTR + rh + i * 8] = v;
    }
  }
  __syncthreads();

  floatx4 acc[2][8];
  #pragma unroll
  for (int mt = 0; mt < 2; mt++)
    #pragma unroll
    for (int nt = 0; nt < 8; nt++) acc[mt][nt] = (floatx4)0.0f;

  #pragma unroll
  for (int kk = 0; kk < 4; kk++) {
    half8 a[2];
    #pragma unroll
    for (int mt = 0; mt < 2; mt++)
      a[mt] = as_h8(*(const uintx4*)(after +
          (size_t)(b * HW + pos0 + wv * 32 + mt * 16 + ln16) * RP + kk * 32 + quad * 8));
    #pragma unroll
    for (int nt = 0; nt < 8; nt++) {
      half8 bf = as_h8(*(const uintx4*)&w_lds[(nt * 16 + ln16) * WSTR + kk * 32 + quad * 8]);
      acc[0][nt] = __builtin_amdgcn_mfma_f32_16x16x32_f16(a[0], bf, acc[0][nt], 0, 0, 0);
      acc[1][nt] = __builtin_amdgcn_mfma_f32_16x16x32_f16(a[1], bf, acc[1][nt], 0, 0, 0);
    }
  }

  #pragma unroll
  for (int nt = 0; nt < 8; nt++) {
    const int co = hc * 128 + nt * 16 + ln16;
    const float bs = bias[co];
    #pragma unroll
    for (int mt = 0; mt < 2; mt++) {
      const int pv = pos0 + wv * 32 + mt * 16 + quad * 4;
      floatx4 v = acc[mt][nt];
      Pk4 pk;
      #pragma unroll
      for (int rr = 0; rr < 4; rr++) pk.u[rr] = f2bf(v[rr] + bs);
      *(uintx2*)(y + (size_t)(b * CB + co) * HW + pv) = pk.v;
    }
  }
}

// ---------------------------------------------------------------------------
// Per-channel batch stats (both sides) over (B, HW): mean and rstd.
// ---------------------------------------------------------------------------
__global__ __launch_bounds__(256) void ra_stats(
    const u16* __restrict__ yL, const u16* __restrict__ yR,
    float* __restrict__ stL, float* __restrict__ stR)
{
  const int side = blockIdx.x >> 8;
  const int c = blockIdx.x & 255;
  const u16* __restrict__ y = side ? yR : yL;
  float* __restrict__ stats = side ? stR : stL;
  const int tid = threadIdx.x;
  float s = 0.f, sq = 0.f;
  for (int b = 0; b < 4; b++) {
    const uintx4* row = (const uintx4*)(y + (size_t)(b * CB + c) * HW);
    #pragma unroll
    for (int t = 0; t < 2; t++) {
      uintx4 rv = row[tid + t * 256];
      #pragma unroll
      for (int k = 0; k < 4; k++) {
        float a0 = bf2f((u16)(rv[k] & 0xffffu));
        float a1 = bf2f((u16)(rv[k] >> 16));
        s += a0 + a1; sq += a0 * a0 + a1 * a1;
      }
    }
  }
  #pragma unroll
  for (int m = 1; m < 64; m <<= 1) { s += __shfl_xor(s, m); sq += __shfl_xor(sq, m); }
  __shared__ float red[8];
  const int wv = tid >> 6;
  if ((tid & 63) == 0) { red[wv * 2] = s; red[wv * 2 + 1] = sq; }
  __syncthreads();
  if (tid == 0) {
    s  = red[0] + red[2] + red[4] + red[6];
    sq = red[1] + red[3] + red[5] + red[7];
    const float mean = s * (1.f / 16384.f);
    const float var  = sq * (1.f / 16384.f) - mean * mean;
    stats[2 * c]     = mean;
    stats[2 * c + 1] = rsqrtf(var + EPSF);
  }
}

// ---------------------------------------------------------------------------
// out = x + gamma*(y - mean)*rstd + beta  (both sides, float4)
// ---------------------------------------------------------------------------
__global__ __launch_bounds__(256) void ra_fin(
    const float* __restrict__ left, const float* __restrict__ right,
    const u16* __restrict__ yL, const u16* __restrict__ yR,
    const float* __restrict__ stL, const float* __restrict__ stR,
    const float* __restrict__ gamma, const float* __restrict__ beta,
    float* __restrict__ out)
{
  const size_t e = (size_t)blockIdx.x * 256 + threadIdx.x;  // global float4 idx
  const int side = (int)(e >> 20);
  const size_t e4 = e & 1048575;
  const int c = (int)((e4 >> 10) & 255);
  const float* x = side ? right : left;
  const u16* y = side ? yR : yL;
  const float* stats = side ? stR : stL;
  const float mean = stats[2 * c], rstd = stats[2 * c + 1];
  const float ga = gamma[c], be = beta[c];
  floatx4 xv = ((const floatx4*)x)[e4];
  uintx2 yv = ((const uintx2*)y)[e4];
  float f0 = bf2f((u16)(yv[0] & 0xffffu));
  float f1 = bf2f((u16)(yv[0] >> 16));
  float f2 = bf2f((u16)(yv[1] & 0xffffu));
  float f3 = bf2f((u16)(yv[1] >> 16));
  floatx4 o;
  o[0] = xv[0] + ga * ((f0 - mean) * rstd) + be;
  o[1] = xv[1] + ga * ((f1 - mean) * rstd) + be;
  o[2] = xv[2] + ga * ((f2 - mean) * rstd) + be;
  o[3] = xv[3] + ga * ((f3 - mean) * rstd) + be;
  ((floatx4*)out)[(size_t)side * 1048576 + e4] = o;
}

// ---------------------------------------------------------------------------
extern "C" void kernel_launch(void* const* d_in, const int* in_sizes, int n_in,
                              void* d_out, int out_size, void* d_ws, size_t ws_size,
                              hipStream_t stream)
{
  const float* left    = (const float*)d_in[0];
  const float* right   = (const float*)d_in[1];
  const float* pre_l   = (const float*)d_in[2];
  const float* pre_r   = (const float*)d_in[3];
  const float* query_l = (const float*)d_in[4];
  const float* key_l   = (const float*)d_in[5];
  const float* query_r = (const float*)d_in[6];
  const float* key_r   = (const float*)d_in[7];
  const float* theta_w = (const float*)d_in[8];
  const float* theta_b = (const float*)d_in[9];
  const float* phi_w   = (const float*)d_in[10];
  const float* phi_b   = (const float*)d_in[11];
  const float* g_w     = (const float*)d_in[12];
  const float* g_b     = (const float*)d_in[13];
  const float* up_w    = (const float*)d_in[14];
  const float* up_b    = (const float*)d_in[15];
  const float* bn_g    = (const float*)d_in[16];
  const float* bn_b    = (const float*)d_in[17];
  float* out = (float*)d_out;

  char* ws = (char*)d_ws;
  const size_t SZ = (size_t)4 * HW * RP * 2;  // 4 MiB (fp16 [4][4096][128])
  u16* thetaL = (u16*)(ws);
  u16* phiTL  = (u16*)(ws + 1 * SZ);
  u16* gTL    = (u16*)(ws + 2 * SZ);
  u16* thetaR = (u16*)(ws + 3 * SZ);
  u16* phiTR  = (u16*)(ws + 4 * SZ);
  u16* gTR    = (u16*)(ws + 5 * SZ);
  u16* afterL = (u16*)(ws + 6 * SZ);
  u16* afterR = (u16*)(ws + 7 * SZ);
  u16* yL     = (u16*)(ws + 8 * SZ);    // 8 MiB
  u16* yR     = (u16*)(ws + 10 * SZ);   // 8 MiB
  float* stL  = (float*)(ws + 12 * SZ);
  float* stR  = (float*)(ws + 12 * SZ + 2048);

  dim3 blk(256);
  // side L: x_q=left, x_kv=right, query_l, key_r; side R mirrored.
  ProjCfg6 pc;
  pc.c[0] = { left,  theta_w, theta_b, query_l, pre_l,   thetaL, 257, 0 };
  pc.c[1] = { right, phi_w,   phi_b,   key_r,   nullptr, phiTL,  256, 0 };
  pc.c[2] = { right, g_w,     g_b,     nullptr, nullptr, gTL,    256, 1 };
  pc.c[3] = { right, theta_w, theta_b, query_r, pre_r,   thetaR, 257, 0 };
  pc.c[4] = { left,  phi_w,   phi_b,   key_l,   nullptr, phiTR,  256, 0 };
  pc.c[5] = { left,  g_w,     g_b,     nullptr, nullptr, gTR,    256, 1 };
  ra_projm<<<768, blk, 0, stream>>>(pc);

  ra_flash<<<512, blk, 0, stream>>>(thetaL, phiTL, gTL, thetaR, phiTR, gTR,
                                    afterL, afterR,
                                    out + 8388608, out + 8404992);
  ra_upm<<<512, blk, 0, stream>>>(afterL, afterR, up_w, up_b, yL, yR);
  ra_stats<<<512, blk, 0, stream>>>(yL, yR, stL, stR);
  ra_fin<<<8192, blk, 0, stream>>>(left, right, yL, yR, stL, stR, bn_g, bn_b, out);

  (void)in_sizes; (void)n_in; (void)out_size; (void)ws_size;
}

// Round 8
// 315.647 us; speedup vs baseline: 1.3207x; 1.0081x over previous
//
#include <hip/hip_runtime.h>

// row_attention_maxindex on MI355X — R12: projm latency fix + stats fusion.
// (1) ra_projm: flash-style register prefetch (chunk c+1 loaded between
//     LDS-write and MFMA of c), barrier_nodrain both barriers (global
//     loads stay in flight across compute), float4 w-loads for 16B-aligned
//     strides (5 of 6 configs). Was: loads -> syncthreads (vmcnt drain!)
//     every chunk = full latency exposed 8x/block.
// (2) ra_stats fused into ra_upm: per-block channel partials (shfl across
//     quads + LDS across waves) -> 2 atomicAdd/channel/block into zeroed
//     stats; ra_fin computes mean/rstd from raw sums. One less dispatch,
//     16MB y re-read gone. hipMemsetAsync zeroes the 4KB stats region.
// ra_flash unchanged from R11 (141us).

typedef unsigned short u16;
typedef unsigned int   u32;
typedef float        floatx4 __attribute__((ext_vector_type(4)));
typedef unsigned int uintx4  __attribute__((ext_vector_type(4)));
typedef unsigned int uintx2  __attribute__((ext_vector_type(2)));
typedef _Float16     half8   __attribute__((ext_vector_type(8)));
typedef __fp16       fp16x2  __attribute__((ext_vector_type(2)));

#define HW 4096
#define CB 256
#define RP 128
#define EPSF 1e-5f

static __device__ __forceinline__ u16 f2bf(float f) {
  u32 u = __float_as_uint(f);
  u32 r = u + 0x7FFFu + ((u >> 16) & 1u);   // RNE
  return (u16)(r >> 16);
}
static __device__ __forceinline__ float bf2f(u16 h) {
  return __uint_as_float(((u32)h) << 16);
}
static __device__ __forceinline__ u16 f2h(float f) {
  _Float16 h = (_Float16)f;                 // RNE
  return __builtin_bit_cast(u16, h);
}
static __device__ __forceinline__ float h2f(u16 h) {
  return (float)__builtin_bit_cast(_Float16, h);
}
static __device__ __forceinline__ half8 as_h8(uintx4 v) {
  return __builtin_bit_cast(half8, v);
}
static __device__ __forceinline__ u32 pkrtz(float a, float b) {
  fp16x2 h = __builtin_amdgcn_cvt_pkrtz(a, b);
  return __builtin_bit_cast(u32, h);
}
static __device__ __forceinline__ u32 pk2h(float a, float b) {  // RNE pair
  return (u32)f2h(a) | ((u32)f2h(b) << 16);
}
// Barrier with DS-visibility only: does NOT drain vmcnt.
static __device__ __forceinline__ void barrier_nodrain() {
  __builtin_amdgcn_sched_barrier(0);
  asm volatile("s_waitcnt lgkmcnt(0)" ::: "memory");
  __builtin_amdgcn_s_barrier();
  __builtin_amdgcn_sched_barrier(0);
}

union Pk4 { u16 u[4]; uintx2 v; };

// ---------------------------------------------------------------------------
// MFMA mega-projection: 6 projections, blockIdx>>7 selects config.
// R12: register prefetch of next chunk + no-drain barriers + float4 w loads.
// ---------------------------------------------------------------------------
struct ProjCfg {
  const float* x; const float* w; const float* bias;
  const float* add; const float* pre; u16* out;
  int wstride; int transposed;
};
struct ProjCfg6 { ProjCfg c[6]; };

#define XSTR 40   // u16 stride of [128][32] fp16 LDS tiles

__global__ __launch_bounds__(256) void ra_projm(ProjCfg6 cfg)
{
  __shared__ u16 x_lds[128 * XSTR];   // [pos][c32]
  __shared__ u16 w_lds[128 * XSTR];   // [r][c32]
  const ProjCfg C = cfg.c[blockIdx.x >> 7];
  const int inner = blockIdx.x & 127;       // b(4) x posb(32)
  const int b    = inner >> 5;
  const int pos0 = (inner & 31) * 128;
  const int tid  = threadIdx.x;
  const int wv   = tid >> 6;
  const int lane = tid & 63;
  const int ln16 = lane & 15;
  const int quad = lane >> 4;
  const int mbase = wv * 32;

  const int xc0 = (tid & 7) * 4, xp0 = (tid >> 3) * 4;   // x: 4c x 4pos
  const int wrr = tid >> 1, wch = (tid & 1) * 16;        // w: 1r x 16c
  const bool walign = (C.wstride & 3) == 0;

  floatx4 acc[2][8];
  #pragma unroll
  for (int mt = 0; mt < 2; mt++)
    #pragma unroll
    for (int nt = 0; nt < 8; nt++) acc[mt][nt] = (floatx4)0.0f;

  floatx4 xr[4];
  floatx4 ww4[4];
  // prefetch chunk 0
  {
    #pragma unroll
    for (int i = 0; i < 4; i++)
      xr[i] = *(const floatx4*)(C.x + (size_t)(b * CB + xc0 + i) * HW + pos0 + xp0);
    const float* wp = C.w + (size_t)wrr * C.wstride + wch;
    if (walign) {
      #pragma unroll
      for (int i = 0; i < 4; i++) ww4[i] = *(const floatx4*)(wp + i * 4);
    } else {
      #pragma unroll
      for (int i = 0; i < 4; i++)
        #pragma unroll
        for (int jj = 0; jj < 4; jj++) ww4[i][jj] = wp[i * 4 + jj];
    }
  }

  #pragma unroll 1
  for (int cc = 0; cc < 8; ++cc) {
    barrier_nodrain();   // prev chunk's LDS reads complete -> safe overwrite
    #pragma unroll
    for (int pp = 0; pp < 4; pp++) {
      uintx2 v;
      v[0] = pk2h(xr[0][pp], xr[1][pp]);
      v[1] = pk2h(xr[2][pp], xr[3][pp]);
      *(uintx2*)&x_lds[(xp0 + pp) * XSTR + xc0] = v;
    }
    {
      uintx4 v0, v1;
      v0[0] = pk2h(ww4[0][0], ww4[0][1]); v0[1] = pk2h(ww4[0][2], ww4[0][3]);
      v0[2] = pk2h(ww4[1][0], ww4[1][1]); v0[3] = pk2h(ww4[1][2], ww4[1][3]);
      v1[0] = pk2h(ww4[2][0], ww4[2][1]); v1[1] = pk2h(ww4[2][2], ww4[2][3]);
      v1[2] = pk2h(ww4[3][0], ww4[3][1]); v1[3] = pk2h(ww4[3][2], ww4[3][3]);
      *(uintx4*)&w_lds[wrr * XSTR + wch]     = v0;
      *(uintx4*)&w_lds[wrr * XSTR + wch + 8] = v1;
    }
    if (cc < 7) {   // prefetch next chunk; stays in flight across MFMA
      const int c2 = (cc + 1) * 32;
      #pragma unroll
      for (int i = 0; i < 4; i++)
        xr[i] = *(const floatx4*)(C.x + (size_t)(b * CB + c2 + xc0 + i) * HW + pos0 + xp0);
      const float* wp = C.w + (size_t)wrr * C.wstride + c2 + wch;
      if (walign) {
        #pragma unroll
        for (int i = 0; i < 4; i++) ww4[i] = *(const floatx4*)(wp + i * 4);
      } else {
        #pragma unroll
        for (int i = 0; i < 4; i++)
          #pragma unroll
          for (int jj = 0; jj < 4; jj++) ww4[i][jj] = wp[i * 4 + jj];
      }
    }
    barrier_nodrain();   // tile visible (lgkm only, vmcnt alive)
    if (!C.transposed) {
      half8 a0 = as_h8(*(const uintx4*)&w_lds[(mbase + ln16) * XSTR + quad * 8]);
      half8 a1 = as_h8(*(const uintx4*)&w_lds[(mbase + 16 + ln16) * XSTR + quad * 8]);
      #pragma unroll
      for (int nt = 0; nt < 8; nt++) {
        half8 bf = as_h8(*(const uintx4*)&x_lds[(nt * 16 + ln16) * XSTR + quad * 8]);
        acc[0][nt] = __builtin_amdgcn_mfma_f32_16x16x32_f16(a0, bf, acc[0][nt], 0, 0, 0);
        acc[1][nt] = __builtin_amdgcn_mfma_f32_16x16x32_f16(a1, bf, acc[1][nt], 0, 0, 0);
      }
    } else {
      half8 a0 = as_h8(*(const uintx4*)&x_lds[(mbase + ln16) * XSTR + quad * 8]);
      half8 a1 = as_h8(*(const uintx4*)&x_lds[(mbase + 16 + ln16) * XSTR + quad * 8]);
      #pragma unroll
      for (int nt = 0; nt < 8; nt++) {
        half8 bf = as_h8(*(const uintx4*)&w_lds[(nt * 16 + ln16) * XSTR + quad * 8]);
        acc[0][nt] = __builtin_amdgcn_mfma_f32_16x16x32_f16(a0, bf, acc[0][nt], 0, 0, 0);
        acc[1][nt] = __builtin_amdgcn_mfma_f32_16x16x32_f16(a1, bf, acc[1][nt], 0, 0, 0);
      }
    }
  }

  if (!C.transposed) {
    #pragma unroll
    for (int mt = 0; mt < 2; mt++) {
      const int r0 = mbase + mt * 16 + quad * 4;
      floatx4 bi = *(const floatx4*)(C.bias + r0);
      float wc[4];
      if (C.pre) {
        #pragma unroll
        for (int rr = 0; rr < 4; rr++) wc[rr] = C.w[(size_t)(r0 + rr) * C.wstride + 256];
      }
      #pragma unroll
      for (int nt = 0; nt < 8; nt++) {
        const int pos = pos0 + nt * 16 + ln16;
        floatx4 v = acc[mt][nt];
        #pragma unroll
        for (int rr = 0; rr < 4; rr++) v[rr] += bi[rr];
        if (C.pre) {
          const float pv = C.pre[(size_t)b * HW + pos] * (1.f / 128.f);
          #pragma unroll
          for (int rr = 0; rr < 4; rr++) v[rr] += pv * wc[rr];
        }
        if (C.add) {
          #pragma unroll
          for (int rr = 0; rr < 4; rr++)
            v[rr] += C.add[(size_t)(b * RP + r0 + rr) * HW + pos];
        }
        Pk4 pk;
        #pragma unroll
        for (int rr = 0; rr < 4; rr++) pk.u[rr] = f2h(v[rr]);
        *(uintx2*)(C.out + (size_t)(b * HW + pos) * RP + r0) = pk.v;
      }
    }
  } else {
    #pragma unroll
    for (int nt = 0; nt < 8; nt++) {
      const int r = nt * 16 + ln16;
      const float bs = C.bias[r];
      #pragma unroll
      for (int mt = 0; mt < 2; mt++) {
        const int pv = pos0 + mbase + mt * 16 + quad * 4;
        floatx4 v = acc[mt][nt];
        Pk4 pk;
        #pragma unroll
        for (int rr = 0; rr < 4; rr++) pk.u[rr] = f2h(v[rr] + bs);
        *(uintx2*)(C.out + (size_t)(b * RP + r) * HW + pv) = pk.v;
      }
    }
  }
}

// ---------------------------------------------------------------------------
// Flash attention, NO split-K (R11): block = (side, b, 64 q), 64 K-tiles.
// l/aC accumulate via PV MFMA colones fragment (even/odd j separated).
// Writes normalized after (fp16) + idx directly.
// ---------------------------------------------------------------------------
__global__ __launch_bounds__(256) void ra_flash(
    const u16* __restrict__ thetaL, const u16* __restrict__ phiTL,
    const u16* __restrict__ gTL,
    const u16* __restrict__ thetaR, const u16* __restrict__ phiTR,
    const u16* __restrict__ gTR,
    u16* __restrict__ afterL, u16* __restrict__ afterR,
    float* __restrict__ idxL, float* __restrict__ idxR)
{
  __shared__ uintx4 phi_lds[16 * 65];   // [rchunk8 cb(16)][k(64)]
  __shared__ uintx4 g_lds[8 * 129];     // [kchunk8 kcb(8)][v(128)]
  __shared__ u16 P_lds[4][16 * 76];     // per-wave [q(16)][k(64)], stride 76

  const int tid  = threadIdx.x;
  const int bx   = blockIdx.x;
  const int side = bx >> 8;
  const int sbx  = bx & 255;
  const u16* __restrict__ theta = side ? thetaR : thetaL;
  const u16* __restrict__ phiT  = side ? phiTR  : phiTL;
  const u16* __restrict__ gT    = side ? gTR    : gTL;

  const int b    = sbx >> 6;
  const int q0   = (sbx & 63) * 64;
  const int wv   = tid >> 6;
  const int lane = tid & 63;
  const int ln16 = lane & 15;
  const int quad = lane >> 4;

  uintx4 aq[4];
  {
    const uintx4* tr = (const uintx4*)(theta + (size_t)(b * HW + q0 + wv * 16 + ln16) * RP);
    #pragma unroll
    for (int c = 0; c < 4; c++) aq[c] = tr[c * 4 + quad];
  }

  // colones A-fragment: row0 = k-in-tile (0..63), row1 = 1, rows 2..15 = 0.
  half8 cf0, cf1;
  {
    #pragma unroll
    for (int i = 0; i < 8; i++) {
      float c0 = (ln16 == 0) ? (float)(quad * 8 + i)      : (ln16 == 1 ? 1.f : 0.f);
      float c1 = (ln16 == 0) ? (float)(32 + quad * 8 + i) : (ln16 == 1 ? 1.f : 0.f);
      cf0[i] = (_Float16)c0;
      cf1[i] = (_Float16)c1;
    }
  }

  floatx4 accO[8];
  #pragma unroll
  for (int v = 0; v < 8; v++) accO[v] = (floatx4)0.0f;
  floatx4 accE  = (floatx4)0.0f;   // even-j: [0]=Σp·kk, [1]=Σp (quad0 rows)
  floatx4 accEo = (floatx4)0.0f;   // odd-j
  float m_q = -3.0e38f;

  const int sk  = tid >> 4, scb = tid & 15;  // phi staging
  const int gv_ = tid >> 3, gcb = tid & 7;   // g staging

  uintx4 sp[4], sg[4];
  #pragma unroll
  for (int i = 0; i < 4; i++) {
    sp[i] = *(const uintx4*)(phiT + (size_t)(b * HW + i * 16 + sk) * RP + scb * 8);
    sg[i] = *(const uintx4*)(gT + (size_t)(b * RP + i * 32 + gv_) * HW + gcb * 8);
  }

  #pragma unroll 1
  for (int j = 0; j < 64; j++) {
    #pragma unroll
    for (int i = 0; i < 4; i++) {
      phi_lds[scb * 65 + i * 16 + sk] = sp[i];
      g_lds[gcb * 129 + i * 32 + gv_] = sg[i];
    }
    if (j < 63) {
      const int k0n = (j + 1) * 64;
      #pragma unroll
      for (int i = 0; i < 4; i++) {
        sp[i] = *(const uintx4*)(phiT + (size_t)(b * HW + k0n + i * 16 + sk) * RP + scb * 8);
        sg[i] = *(const uintx4*)(gT + (size_t)(b * RP + i * 32 + gv_) * HW + k0n + gcb * 8);
      }
    }
    barrier_nodrain();

    floatx4 sf[4];
    #pragma unroll
    for (int s = 0; s < 4; s++) sf[s] = (floatx4)0.0f;
    __builtin_amdgcn_s_setprio(1);
    #pragma unroll
    for (int c = 0; c < 4; c++) {
      half8 bth = as_h8(aq[c]);
      #pragma unroll
      for (int s = 0; s < 4; s++) {
        uintx4 ap = phi_lds[(c * 4 + quad) * 65 + s * 16 + ln16];
        sf[s] = __builtin_amdgcn_mfma_f32_16x16x32_f16(as_h8(ap), bth, sf[s], 0, 0, 0);
      }
    }
    __builtin_amdgcn_s_setprio(0);

    float ms0 = fmaxf(fmaxf(sf[0][0], sf[0][1]), fmaxf(sf[0][2], sf[0][3]));
    float ms1 = fmaxf(fmaxf(sf[1][0], sf[1][1]), fmaxf(sf[1][2], sf[1][3]));
    float ms2 = fmaxf(fmaxf(sf[2][0], sf[2][1]), fmaxf(sf[2][2], sf[2][3]));
    float ms3 = fmaxf(fmaxf(sf[3][0], sf[3][1]), fmaxf(sf[3][2], sf[3][3]));
    float mx = fmaxf(fmaxf(ms0, ms1), fmaxf(ms2, ms3));
    mx = fmaxf(mx, __shfl_xor(mx, 16));
    mx = fmaxf(mx, __shfl_xor(mx, 32));
    if (__any(mx > m_q + 8.f)) {       // wave-uniform, rare in steady state
      const float mnew  = fmaxf(m_q, mx);
      const float alpha = __expf(m_q - mnew);
      m_q = mnew;
      accE *= alpha; accEo *= alpha;
      #pragma unroll
      for (int v = 0; v < 8; v++) accO[v] *= alpha;
    }
    #pragma unroll
    for (int s = 0; s < 4; s++) {
      float p0 = __expf(sf[s][0] - m_q);
      float p1 = __expf(sf[s][1] - m_q);
      float p2 = __expf(sf[s][2] - m_q);
      float p3 = __expf(sf[s][3] - m_q);
      uintx2 pkv;
      pkv[0] = pkrtz(p0, p1);
      pkv[1] = pkrtz(p2, p3);
      *(uintx2*)&P_lds[wv][ln16 * 76 + s * 16 + quad * 4] = pkv;
    }

    // no barrier: P_lds is wave-private; DS ops in-order per wave.
    half8 pb0 = as_h8(*(const uintx4*)&P_lds[wv][ln16 * 76 + quad * 8]);
    half8 pb1 = as_h8(*(const uintx4*)&P_lds[wv][ln16 * 76 + 32 + quad * 8]);
    __builtin_amdgcn_s_setprio(1);
    #pragma unroll
    for (int vt = 0; vt < 8; vt++) {
      uintx4 ag0 = g_lds[quad * 129 + vt * 16 + ln16];
      uintx4 ag1 = g_lds[(4 + quad) * 129 + vt * 16 + ln16];
      accO[vt] = __builtin_amdgcn_mfma_f32_16x16x32_f16(as_h8(ag0), pb0, accO[vt], 0, 0, 0);
      accO[vt] = __builtin_amdgcn_mfma_f32_16x16x32_f16(as_h8(ag1), pb1, accO[vt], 0, 0, 0);
    }
    if (j & 1) {
      accEo = __builtin_amdgcn_mfma_f32_16x16x32_f16(cf0, pb0, accEo, 0, 0, 0);
      accEo = __builtin_amdgcn_mfma_f32_16x16x32_f16(cf1, pb1, accEo, 0, 0, 0);
    } else {
      accE  = __builtin_amdgcn_mfma_f32_16x16x32_f16(cf0, pb0, accE, 0, 0, 0);
      accE  = __builtin_amdgcn_mfma_f32_16x16x32_f16(cf1, pb1, accE, 0, 0, 0);
    }
    __builtin_amdgcn_s_setprio(0);
    barrier_nodrain();
  }

  // epilogue: l = Σp (all j), aC = Σp·kk + 64·Σp(odd j); broadcast via shfl.
  const float l0 = accE[1] + accEo[1];
  const float a0 = accE[0] + accEo[0] + 64.f * accEo[1];
  const float l_all  = __shfl(l0, ln16);
  const float aC_all = __shfl(a0, ln16);

  const int q = q0 + wv * 16 + ln16;
  const size_t p = (size_t)b * HW + q;
  u16* after = side ? afterR : afterL;
  u16* orow = after + p * RP;
  const float invl = 1.f / l_all;
  #pragma unroll
  for (int vt = 0; vt < 8; vt++) {
    uintx2 pkv;
    pkv[0] = pkrtz(accO[vt][0] * invl, accO[vt][1] * invl);
    pkv[1] = pkrtz(accO[vt][2] * invl, accO[vt][3] * invl);
    *(uintx2*)(orow + vt * 16 + quad * 4) = pkv;
  }
  if (quad == 0) {
    float* idx = side ? idxR : idxL;
    idx[p] = (float)(q & 127) - aC_all * invl;
  }
}

// ---------------------------------------------------------------------------
// MFMA up-projection + fused batch stats.
// y[b,co,pos] = after[b,pos,:]·up_w[co,:] + up_b; per-channel Σy, Σy² go
// through in-register quad reduce -> LDS wave reduce -> 2 atomicAdd/ch.
// stats arrays must be zeroed before this kernel (memsetAsync in launch).
// ---------------------------------------------------------------------------
#define WSTR 136   // u16 stride (272B, 16B-aligned rows)

__global__ __launch_bounds__(256) void ra_upm(
    const u16* __restrict__ afterL, const u16* __restrict__ afterR,
    const float* __restrict__ w, const float* __restrict__ bias,
    u16* __restrict__ yL, u16* __restrict__ yR,
    float* __restrict__ stL, float* __restrict__ stR)
{
  __shared__ u16 w_lds[128 * WSTR];   // [co][r]; reused as float scratch
  const int tid  = threadIdx.x;
  const int bx   = blockIdx.x;
  const int side = bx >> 8;
  const int sbx  = bx & 255;
  const u16* __restrict__ after = side ? afterR : afterL;
  u16* __restrict__ y = side ? yR : yL;
  const int b    = sbx >> 6;
  const int pos0 = ((sbx >> 1) & 31) * 128;
  const int hc   = sbx & 1;
  const int wv   = tid >> 6;
  const int lane = tid & 63;
  const int ln16 = lane & 15;
  const int quad = lane >> 4;

  {
    const int co = tid >> 1, rh = (tid & 1) * 64;
    const float* wp = w + (size_t)(hc * 128 + co) * RP + rh;
    #pragma unroll
    for (int i = 0; i < 8; i++) {
      floatx4 f0 = *(const floatx4*)(wp + i * 8);
      floatx4 f1 = *(const floatx4*)(wp + i * 8 + 4);
      uintx4 v;
      v[0] = pk2h(f0[0], f0[1]); v[1] = pk2h(f0[2], f0[3]);
      v[2] = pk2h(f1[0], f1[1]); v[3] = pk2h(f1[2], f1[3]);
      *(uintx4*)&w_lds[co * WSTR + rh + i * 8] = v;
    }
  }
  __syncthreads();

  floatx4 acc[2][8];
  #pragma unroll
  for (int mt = 0; mt < 2; mt++)
    #pragma unroll
    for (int nt = 0; nt < 8; nt++) acc[mt][nt] = (floatx4)0.0f;

  #pragma unroll
  for (int kk = 0; kk < 4; kk++) {
    half8 a[2];
    #pragma unroll
    for (int mt = 0; mt < 2; mt++)
      a[mt] = as_h8(*(const uintx4*)(after +
          (size_t)(b * HW + pos0 + wv * 32 + mt * 16 + ln16) * RP + kk * 32 + quad * 8));
    #pragma unroll
    for (int nt = 0; nt < 8; nt++) {
      half8 bf = as_h8(*(const uintx4*)&w_lds[(nt * 16 + ln16) * WSTR + kk * 32 + quad * 8]);
      acc[0][nt] = __builtin_amdgcn_mfma_f32_16x16x32_f16(a[0], bf, acc[0][nt], 0, 0, 0);
      acc[1][nt] = __builtin_amdgcn_mfma_f32_16x16x32_f16(a[1], bf, acc[1][nt], 0, 0, 0);
    }
  }

  // y store + per-channel partials (this block: 128 pos of one b)
  float s_nt[8], q_nt[8];
  #pragma unroll
  for (int nt = 0; nt < 8; nt++) {
    const int co = hc * 128 + nt * 16 + ln16;
    const float bs = bias[co];
    float s = 0.f, sq = 0.f;
    #pragma unroll
    for (int mt = 0; mt < 2; mt++) {
      const int pv = pos0 + wv * 32 + mt * 16 + quad * 4;
      floatx4 v = acc[mt][nt];
      Pk4 pk;
      #pragma unroll
      for (int rr = 0; rr < 4; rr++) {
        const float yv = v[rr] + bs;
        s += yv; sq += yv * yv;
        pk.u[rr] = f2bf(yv);
      }
      *(uintx2*)(y + (size_t)(b * CB + co) * HW + pv) = pk.v;
    }
    s  += __shfl_xor(s, 16);  s  += __shfl_xor(s, 32);
    sq += __shfl_xor(sq, 16); sq += __shfl_xor(sq, 32);
    s_nt[nt] = s; q_nt[nt] = sq;
  }
  __syncthreads();              // all waves done reading w_lds
  float* scr = (float*)w_lds;   // [0..511]=s per (wv,co), [512..1023]=sq
  if (quad == 0) {
    #pragma unroll
    for (int nt = 0; nt < 8; nt++) {
      scr[wv * 128 + nt * 16 + ln16]       = s_nt[nt];
      scr[512 + wv * 128 + nt * 16 + ln16] = q_nt[nt];
    }
  }
  __syncthreads();
  if (tid < 128) {
    const float s  = scr[tid] + scr[128 + tid] + scr[256 + tid] + scr[384 + tid];
    const float sq = scr[512 + tid] + scr[640 + tid] + scr[768 + tid] + scr[896 + tid];
    float* stats = side ? stR : stL;
    atomicAdd(&stats[2 * (hc * 128 + tid)], s);
    atomicAdd(&stats[2 * (hc * 128 + tid) + 1], sq);
  }
}

// ---------------------------------------------------------------------------
// out = x + gamma*(y - mean)*rstd + beta. stats hold raw Σy, Σy².
// ---------------------------------------------------------------------------
__global__ __launch_bounds__(256) void ra_fin(
    const float* __restrict__ left, const float* __restrict__ right,
    const u16* __restrict__ yL, const u16* __restrict__ yR,
    const float* __restrict__ stL, const float* __restrict__ stR,
    const float* __restrict__ gamma, const float* __restrict__ beta,
    float* __restrict__ out)
{
  const size_t e = (size_t)blockIdx.x * 256 + threadIdx.x;  // global float4 idx
  const int side = (int)(e >> 20);
  const size_t e4 = e & 1048575;
  const int c = (int)((e4 >> 10) & 255);
  const float* x = side ? right : left;
  const u16* y = side ? yR : yL;
  const float* stats = side ? stR : stL;
  const float s = stats[2 * c], sq = stats[2 * c + 1];
  const float mean = s * (1.f / 16384.f);
  const float var  = sq * (1.f / 16384.f) - mean * mean;
  const float rstd = rsqrtf(var + EPSF);
  const float ga = gamma[c], be = beta[c];
  floatx4 xv = ((const floatx4*)x)[e4];
  uintx2 yv = ((const uintx2*)y)[e4];
  float f0 = bf2f((u16)(yv[0] & 0xffffu));
  float f1 = bf2f((u16)(yv[0] >> 16));
  float f2 = bf2f((u16)(yv[1] & 0xffffu));
  float f3 = bf2f((u16)(yv[1] >> 16));
  floatx4 o;
  o[0] = xv[0] + ga * ((f0 - mean) * rstd) + be;
  o[1] = xv[1] + ga * ((f1 - mean) * rstd) + be;
  o[2] = xv[2] + ga * ((f2 - mean) * rstd) + be;
  o[3] = xv[3] + ga * ((f3 - mean) * rstd) + be;
  ((floatx4*)out)[(size_t)side * 1048576 + e4] = o;
}

// ---------------------------------------------------------------------------
extern "C" void kernel_launch(void* const* d_in, const int* in_sizes, int n_in,
                              void* d_out, int out_size, void* d_ws, size_t ws_size,
                              hipStream_t stream)
{
  const float* left    = (const float*)d_in[0];
  const float* right   = (const float*)d_in[1];
  const float* pre_l   = (const float*)d_in[2];
  const float* pre_r   = (const float*)d_in[3];
  const float* query_l = (const float*)d_in[4];
  const float* key_l   = (const float*)d_in[5];
  const float* query_r = (const float*)d_in[6];
  const float* key_r   = (const float*)d_in[7];
  const float* theta_w = (const float*)d_in[8];
  const float* theta_b = (const float*)d_in[9];
  const float* phi_w   = (const float*)d_in[10];
  const float* phi_b   = (const float*)d_in[11];
  const float* g_w     = (const float*)d_in[12];
  const float* g_b     = (const float*)d_in[13];
  const float* up_w    = (const float*)d_in[14];
  const float* up_b    = (const float*)d_in[15];
  const float* bn_g    = (const float*)d_in[16];
  const float* bn_b    = (const float*)d_in[17];
  float* out = (float*)d_out;

  char* ws = (char*)d_ws;
  const size_t SZ = (size_t)4 * HW * RP * 2;  // 4 MiB (fp16 [4][4096][128])
  u16* thetaL = (u16*)(ws);
  u16* phiTL  = (u16*)(ws + 1 * SZ);
  u16* gTL    = (u16*)(ws + 2 * SZ);
  u16* thetaR = (u16*)(ws + 3 * SZ);
  u16* phiTR  = (u16*)(ws + 4 * SZ);
  u16* gTR    = (u16*)(ws + 5 * SZ);
  u16* afterL = (u16*)(ws + 6 * SZ);
  u16* afterR = (u16*)(ws + 7 * SZ);
  u16* yL     = (u16*)(ws + 8 * SZ);    // 8 MiB
  u16* yR     = (u16*)(ws + 10 * SZ);   // 8 MiB
  float* stL  = (float*)(ws + 12 * SZ);
  float* stR  = (float*)(ws + 12 * SZ + 2048);

  hipMemsetAsync(ws + 12 * SZ, 0, 4096, stream);   // zero stats accumulators

  dim3 blk(256);
  // side L: x_q=left, x_kv=right, query_l, key_r; side R mirrored.
  ProjCfg6 pc;
  pc.c[0] = { left,  theta_w, theta_b, query_l, pre_l,   thetaL, 257, 0 };
  pc.c[1] = { right, phi_w,   phi_b,   key_r,   nullptr, phiTL,  256, 0 };
  pc.c[2] = { right, g_w,     g_b,     nullptr, nullptr, gTL,    256, 1 };
  pc.c[3] = { right, theta_w, theta_b, query_r, pre_r,   thetaR, 257, 0 };
  pc.c[4] = { left,  phi_w,   phi_b,   key_l,   nullptr, phiTR,  256, 0 };
  pc.c[5] = { left,  g_w,     g_b,     nullptr, nullptr, gTR,    256, 1 };
  ra_projm<<<768, blk, 0, stream>>>(pc);

  ra_flash<<<512, blk, 0, stream>>>(thetaL, phiTL, gTL, thetaR, phiTR, gTR,
                                    afterL, afterR,
                                    out + 8388608, out + 8404992);
  ra_upm<<<512, blk, 0, stream>>>(afterL, afterR, up_w, up_b, yL, yR, stL, stR);
  ra_fin<<<8192, blk, 0, stream>>>(left, right, yL, yR, stL, stR, bn_g, bn_b, out);

  (void)in_sizes; (void)n_in; (void)out_size; (void)ws_size;
}

// Round 10
// 312.606 us; speedup vs baseline: 1.3335x; 1.0097x over previous
//
#include <hip/hip_runtime.h>

// row_attention_maxindex on MI355X — R14: revert to R12 (known-good 315.6us)
// after R13's cooperative-launch failure (hipLaunchCooperativeKernel is
// incompatible with the harness's stream/graph path; out was never written).
// Delta vs R12: stats zeroing moved into ra_projm block 0 (drops the
// hipMemsetAsync dispatch). projm R12-prefetch, flash R11-colones,
// upm fused stats, fin from raw sums — all unchanged.

typedef unsigned short u16;
typedef unsigned int   u32;
typedef float        floatx4 __attribute__((ext_vector_type(4)));
typedef unsigned int uintx4  __attribute__((ext_vector_type(4)));
typedef unsigned int uintx2  __attribute__((ext_vector_type(2)));
typedef _Float16     half8   __attribute__((ext_vector_type(8)));
typedef __fp16       fp16x2  __attribute__((ext_vector_type(2)));

#define HW 4096
#define CB 256
#define RP 128
#define EPSF 1e-5f

static __device__ __forceinline__ u16 f2bf(float f) {
  u32 u = __float_as_uint(f);
  u32 r = u + 0x7FFFu + ((u >> 16) & 1u);   // RNE
  return (u16)(r >> 16);
}
static __device__ __forceinline__ float bf2f(u16 h) {
  return __uint_as_float(((u32)h) << 16);
}
static __device__ __forceinline__ u16 f2h(float f) {
  _Float16 h = (_Float16)f;                 // RNE
  return __builtin_bit_cast(u16, h);
}
static __device__ __forceinline__ float h2f(u16 h) {
  return (float)__builtin_bit_cast(_Float16, h);
}
static __device__ __forceinline__ half8 as_h8(uintx4 v) {
  return __builtin_bit_cast(half8, v);
}
static __device__ __forceinline__ u32 pkrtz(float a, float b) {
  fp16x2 h = __builtin_amdgcn_cvt_pkrtz(a, b);
  return __builtin_bit_cast(u32, h);
}
static __device__ __forceinline__ u32 pk2h(float a, float b) {  // RNE pair
  return (u32)f2h(a) | ((u32)f2h(b) << 16);
}
// Barrier with DS-visibility only: does NOT drain vmcnt.
static __device__ __forceinline__ void barrier_nodrain() {
  __builtin_amdgcn_sched_barrier(0);
  asm volatile("s_waitcnt lgkmcnt(0)" ::: "memory");
  __builtin_amdgcn_s_barrier();
  __builtin_amdgcn_sched_barrier(0);
}

union Pk4 { u16 u[4]; uintx2 v; };

// ---------------------------------------------------------------------------
// MFMA mega-projection: 6 projections, blockIdx>>7 selects config.
// R12 structure: register prefetch of next chunk + no-drain barriers +
// float4 w loads. R14: block 0 zeroes the stats accumulators (4KB).
// ---------------------------------------------------------------------------
struct ProjCfg {
  const float* x; const float* w; const float* bias;
  const float* add; const float* pre; u16* out;
  int wstride; int transposed;
};
struct ProjCfg6 { ProjCfg c[6]; };

#define XSTR 40   // u16 stride of [128][32] fp16 LDS tiles

__global__ __launch_bounds__(256) void ra_projm(ProjCfg6 cfg, float* stz)
{
  __shared__ u16 x_lds[128 * XSTR];   // [pos][c32]
  __shared__ u16 w_lds[128 * XSTR];   // [r][c32]
  if (blockIdx.x == 0) {              // zero stats accumulators (1024 floats)
    ((floatx4*)stz)[threadIdx.x] = (floatx4)0.0f;
  }
  const ProjCfg C = cfg.c[blockIdx.x >> 7];
  const int inner = blockIdx.x & 127;       // b(4) x posb(32)
  const int b    = inner >> 5;
  const int pos0 = (inner & 31) * 128;
  const int tid  = threadIdx.x;
  const int wv   = tid >> 6;
  const int lane = tid & 63;
  const int ln16 = lane & 15;
  const int quad = lane >> 4;
  const int mbase = wv * 32;

  const int xc0 = (tid & 7) * 4, xp0 = (tid >> 3) * 4;   // x: 4c x 4pos
  const int wrr = tid >> 1, wch = (tid & 1) * 16;        // w: 1r x 16c
  const bool walign = (C.wstride & 3) == 0;

  floatx4 acc[2][8];
  #pragma unroll
  for (int mt = 0; mt < 2; mt++)
    #pragma unroll
    for (int nt = 0; nt < 8; nt++) acc[mt][nt] = (floatx4)0.0f;

  floatx4 xr[4];
  floatx4 ww4[4];
  {
    #pragma unroll
    for (int i = 0; i < 4; i++)
      xr[i] = *(const floatx4*)(C.x + (size_t)(b * CB + xc0 + i) * HW + pos0 + xp0);
    const float* wp = C.w + (size_t)wrr * C.wstride + wch;
    if (walign) {
      #pragma unroll
      for (int i = 0; i < 4; i++) ww4[i] = *(const floatx4*)(wp + i * 4);
    } else {
      #pragma unroll
      for (int i = 0; i < 4; i++)
        #pragma unroll
        for (int jj = 0; jj < 4; jj++) ww4[i][jj] = wp[i * 4 + jj];
    }
  }

  #pragma unroll 1
  for (int cc = 0; cc < 8; ++cc) {
    barrier_nodrain();   // prev chunk's LDS reads complete -> safe overwrite
    #pragma unroll
    for (int pp = 0; pp < 4; pp++) {
      uintx2 v;
      v[0] = pk2h(xr[0][pp], xr[1][pp]);
      v[1] = pk2h(xr[2][pp], xr[3][pp]);
      *(uintx2*)&x_lds[(xp0 + pp) * XSTR + xc0] = v;
    }
    {
      uintx4 v0, v1;
      v0[0] = pk2h(ww4[0][0], ww4[0][1]); v0[1] = pk2h(ww4[0][2], ww4[0][3]);
      v0[2] = pk2h(ww4[1][0], ww4[1][1]); v0[3] = pk2h(ww4[1][2], ww4[1][3]);
      v1[0] = pk2h(ww4[2][0], ww4[2][1]); v1[1] = pk2h(ww4[2][2], ww4[2][3]);
      v1[2] = pk2h(ww4[3][0], ww4[3][1]); v1[3] = pk2h(ww4[3][2], ww4[3][3]);
      *(uintx4*)&w_lds[wrr * XSTR + wch]     = v0;
      *(uintx4*)&w_lds[wrr * XSTR + wch + 8] = v1;
    }
    if (cc < 7) {   // prefetch next chunk; stays in flight across MFMA
      const int c2 = (cc + 1) * 32;
      #pragma unroll
      for (int i = 0; i < 4; i++)
        xr[i] = *(const floatx4*)(C.x + (size_t)(b * CB + c2 + xc0 + i) * HW + pos0 + xp0);
      const float* wp = C.w + (size_t)wrr * C.wstride + c2 + wch;
      if (walign) {
        #pragma unroll
        for (int i = 0; i < 4; i++) ww4[i] = *(const floatx4*)(wp + i * 4);
      } else {
        #pragma unroll
        for (int i = 0; i < 4; i++)
          #pragma unroll
          for (int jj = 0; jj < 4; jj++) ww4[i][jj] = wp[i * 4 + jj];
      }
    }
    barrier_nodrain();   // tile visible (lgkm only, vmcnt alive)
    if (!C.transposed) {
      half8 a0 = as_h8(*(const uintx4*)&w_lds[(mbase + ln16) * XSTR + quad * 8]);
      half8 a1 = as_h8(*(const uintx4*)&w_lds[(mbase + 16 + ln16) * XSTR + quad * 8]);
      #pragma unroll
      for (int nt = 0; nt < 8; nt++) {
        half8 bf = as_h8(*(const uintx4*)&x_lds[(nt * 16 + ln16) * XSTR + quad * 8]);
        acc[0][nt] = __builtin_amdgcn_mfma_f32_16x16x32_f16(a0, bf, acc[0][nt], 0, 0, 0);
        acc[1][nt] = __builtin_amdgcn_mfma_f32_16x16x32_f16(a1, bf, acc[1][nt], 0, 0, 0);
      }
    } else {
      half8 a0 = as_h8(*(const uintx4*)&x_lds[(mbase + ln16) * XSTR + quad * 8]);
      half8 a1 = as_h8(*(const uintx4*)&x_lds[(mbase + 16 + ln16) * XSTR + quad * 8]);
      #pragma unroll
      for (int nt = 0; nt < 8; nt++) {
        half8 bf = as_h8(*(const uintx4*)&w_lds[(nt * 16 + ln16) * XSTR + quad * 8]);
        acc[0][nt] = __builtin_amdgcn_mfma_f32_16x16x32_f16(a0, bf, acc[0][nt], 0, 0, 0);
        acc[1][nt] = __builtin_amdgcn_mfma_f32_16x16x32_f16(a1, bf, acc[1][nt], 0, 0, 0);
      }
    }
  }

  if (!C.transposed) {
    #pragma unroll
    for (int mt = 0; mt < 2; mt++) {
      const int r0 = mbase + mt * 16 + quad * 4;
      floatx4 bi = *(const floatx4*)(C.bias + r0);
      float wc[4];
      if (C.pre) {
        #pragma unroll
        for (int rr = 0; rr < 4; rr++) wc[rr] = C.w[(size_t)(r0 + rr) * C.wstride + 256];
      }
      #pragma unroll
      for (int nt = 0; nt < 8; nt++) {
        const int pos = pos0 + nt * 16 + ln16;
        floatx4 v = acc[mt][nt];
        #pragma unroll
        for (int rr = 0; rr < 4; rr++) v[rr] += bi[rr];
        if (C.pre) {
          const float pv = C.pre[(size_t)b * HW + pos] * (1.f / 128.f);
          #pragma unroll
          for (int rr = 0; rr < 4; rr++) v[rr] += pv * wc[rr];
        }
        if (C.add) {
          #pragma unroll
          for (int rr = 0; rr < 4; rr++)
            v[rr] += C.add[(size_t)(b * RP + r0 + rr) * HW + pos];
        }
        Pk4 pk;
        #pragma unroll
        for (int rr = 0; rr < 4; rr++) pk.u[rr] = f2h(v[rr]);
        *(uintx2*)(C.out + (size_t)(b * HW + pos) * RP + r0) = pk.v;
      }
    }
  } else {
    #pragma unroll
    for (int nt = 0; nt < 8; nt++) {
      const int r = nt * 16 + ln16;
      const float bs = C.bias[r];
      #pragma unroll
      for (int mt = 0; mt < 2; mt++) {
        const int pv = pos0 + mbase + mt * 16 + quad * 4;
        floatx4 v = acc[mt][nt];
        Pk4 pk;
        #pragma unroll
        for (int rr = 0; rr < 4; rr++) pk.u[rr] = f2h(v[rr] + bs);
        *(uintx2*)(C.out + (size_t)(b * RP + r) * HW + pv) = pk.v;
      }
    }
  }
}

// ---------------------------------------------------------------------------
// Flash attention, NO split-K (R11): block = (side, b, 64 q), 64 K-tiles.
// l/aC accumulate via PV MFMA colones fragment (even/odd j separated).
// Writes normalized after (fp16) + idx directly.
// ---------------------------------------------------------------------------
__global__ __launch_bounds__(256) void ra_flash(
    const u16* __restrict__ thetaL, const u16* __restrict__ phiTL,
    const u16* __restrict__ gTL,
    const u16* __restrict__ thetaR, const u16* __restrict__ phiTR,
    const u16* __restrict__ gTR,
    u16* __restrict__ afterL, u16* __restrict__ afterR,
    float* __restrict__ idxL, float* __restrict__ idxR)
{
  __shared__ uintx4 phi_lds[16 * 65];   // [rchunk8 cb(16)][k(64)]
  __shared__ uintx4 g_lds[8 * 129];     // [kchunk8 kcb(8)][v(128)]
  __shared__ u16 P_lds[4][16 * 76];     // per-wave [q(16)][k(64)], stride 76

  const int tid  = threadIdx.x;
  const int bx   = blockIdx.x;
  const int side = bx >> 8;
  const int sbx  = bx & 255;
  const u16* __restrict__ theta = side ? thetaR : thetaL;
  const u16* __restrict__ phiT  = side ? phiTR  : phiTL;
  const u16* __restrict__ gT    = side ? gTR    : gTL;

  const int b    = sbx >> 6;
  const int q0   = (sbx & 63) * 64;
  const int wv   = tid >> 6;
  const int lane = tid & 63;
  const int ln16 = lane & 15;
  const int quad = lane >> 4;

  uintx4 aq[4];
  {
    const uintx4* tr = (const uintx4*)(theta + (size_t)(b * HW + q0 + wv * 16 + ln16) * RP);
    #pragma unroll
    for (int c = 0; c < 4; c++) aq[c] = tr[c * 4 + quad];
  }

  // colones A-fragment: row0 = k-in-tile (0..63), row1 = 1, rows 2..15 = 0.
  half8 cf0, cf1;
  {
    #pragma unroll
    for (int i = 0; i < 8; i++) {
      float c0 = (ln16 == 0) ? (float)(quad * 8 + i)      : (ln16 == 1 ? 1.f : 0.f);
      float c1 = (ln16 == 0) ? (float)(32 + quad * 8 + i) : (ln16 == 1 ? 1.f : 0.f);
      cf0[i] = (_Float16)c0;
      cf1[i] = (_Float16)c1;
    }
  }

  floatx4 accO[8];
  #pragma unroll
  for (int v = 0; v < 8; v++) accO[v] = (floatx4)0.0f;
  floatx4 accE  = (floatx4)0.0f;   // even-j: [0]=Σp·kk, [1]=Σp (quad0 rows)
  floatx4 accEo = (floatx4)0.0f;   // odd-j
  float m_q = -3.0e38f;

  const int sk  = tid >> 4, scb = tid & 15;  // phi staging
  const int gv_ = tid >> 3, gcb = tid & 7;   // g staging

  uintx4 sp[4], sg[4];
  #pragma unroll
  for (int i = 0; i < 4; i++) {
    sp[i] = *(const uintx4*)(phiT + (size_t)(b * HW + i * 16 + sk) * RP + scb * 8);
    sg[i] = *(const uintx4*)(gT + (size_t)(b * RP + i * 32 + gv_) * HW + gcb * 8);
  }

  #pragma unroll 1
  for (int j = 0; j < 64; j++) {
    #pragma unroll
    for (int i = 0; i < 4; i++) {
      phi_lds[scb * 65 + i * 16 + sk] = sp[i];
      g_lds[gcb * 129 + i * 32 + gv_] = sg[i];
    }
    if (j < 63) {
      const int k0n = (j + 1) * 64;
      #pragma unroll
      for (int i = 0; i < 4; i++) {
        sp[i] = *(const uintx4*)(phiT + (size_t)(b * HW + k0n + i * 16 + sk) * RP + scb * 8);
        sg[i] = *(const uintx4*)(gT + (size_t)(b * RP + i * 32 + gv_) * HW + k0n + gcb * 8);
      }
    }
    barrier_nodrain();

    floatx4 sf[4];
    #pragma unroll
    for (int s = 0; s < 4; s++) sf[s] = (floatx4)0.0f;
    __builtin_amdgcn_s_setprio(1);
    #pragma unroll
    for (int c = 0; c < 4; c++) {
      half8 bth = as_h8(aq[c]);
      #pragma unroll
      for (int s = 0; s < 4; s++) {
        uintx4 ap = phi_lds[(c * 4 + quad) * 65 + s * 16 + ln16];
        sf[s] = __builtin_amdgcn_mfma_f32_16x16x32_f16(as_h8(ap), bth, sf[s], 0, 0, 0);
      }
    }
    __builtin_amdgcn_s_setprio(0);

    float ms0 = fmaxf(fmaxf(sf[0][0], sf[0][1]), fmaxf(sf[0][2], sf[0][3]));
    float ms1 = fmaxf(fmaxf(sf[1][0], sf[1][1]), fmaxf(sf[1][2], sf[1][3]));
    float ms2 = fmaxf(fmaxf(sf[2][0], sf[2][1]), fmaxf(sf[2][2], sf[2][3]));
    float ms3 = fmaxf(fmaxf(sf[3][0], sf[3][1]), fmaxf(sf[3][2], sf[3][3]));
    float mx = fmaxf(fmaxf(ms0, ms1), fmaxf(ms2, ms3));
    mx = fmaxf(mx, __shfl_xor(mx, 16));
    mx = fmaxf(mx, __shfl_xor(mx, 32));
    if (__any(mx > m_q + 8.f)) {       // wave-uniform, rare in steady state
      const float mnew  = fmaxf(m_q, mx);
      const float alpha = __expf(m_q - mnew);
      m_q = mnew;
      accE *= alpha; accEo *= alpha;
      #pragma unroll
      for (int v = 0; v < 8; v++) accO[v] *= alpha;
    }
    #pragma unroll
    for (int s = 0; s < 4; s++) {
      float p0 = __expf(sf[s][0] - m_q);
      float p1 = __expf(sf[s][1] - m_q);
      float p2 = __expf(sf[s][2] - m_q);
      float p3 = __expf(sf[s][3] - m_q);
      uintx2 pkv;
      pkv[0] = pkrtz(p0, p1);
      pkv[1] = pkrtz(p2, p3);
      *(uintx2*)&P_lds[wv][ln16 * 76 + s * 16 + quad * 4] = pkv;
    }

    // no barrier: P_lds is wave-private; DS ops in-order per wave.
    half8 pb0 = as_h8(*(const uintx4*)&P_lds[wv][ln16 * 76 + quad * 8]);
    half8 pb1 = as_h8(*(const uintx4*)&P_lds[wv][ln16 * 76 + 32 + quad * 8]);
    __builtin_amdgcn_s_setprio(1);
    #pragma unroll
    for (int vt = 0; vt < 8; vt++) {
      uintx4 ag0 = g_lds[quad * 129 + vt * 16 + ln16];
      uintx4 ag1 = g_lds[(4 + quad) * 129 + vt * 16 + ln16];
      accO[vt] = __builtin_amdgcn_mfma_f32_16x16x32_f16(as_h8(ag0), pb0, accO[vt], 0, 0, 0);
      accO[vt] = __builtin_amdgcn_mfma_f32_16x16x32_f16(as_h8(ag1), pb1, accO[vt], 0, 0, 0);
    }
    if (j & 1) {
      accEo = __builtin_amdgcn_mfma_f32_16x16x32_f16(cf0, pb0, accEo, 0, 0, 0);
      accEo = __builtin_amdgcn_mfma_f32_16x16x32_f16(cf1, pb1, accEo, 0, 0, 0);
    } else {
      accE  = __builtin_amdgcn_mfma_f32_16x16x32_f16(cf0, pb0, accE, 0, 0, 0);
      accE  = __builtin_amdgcn_mfma_f32_16x16x32_f16(cf1, pb1, accE, 0, 0, 0);
    }
    __builtin_amdgcn_s_setprio(0);
    barrier_nodrain();
  }

  // epilogue: l = Σp (all j), aC = Σp·kk + 64·Σp(odd j); broadcast via shfl.
  const float l0 = accE[1] + accEo[1];
  const float a0 = accE[0] + accEo[0] + 64.f * accEo[1];
  const float l_all  = __shfl(l0, ln16);
  const float aC_all = __shfl(a0, ln16);

  const int q = q0 + wv * 16 + ln16;
  const size_t p = (size_t)b * HW + q;
  u16* after = side ? afterR : afterL;
  u16* orow = after + p * RP;
  const float invl = 1.f / l_all;
  #pragma unroll
  for (int vt = 0; vt < 8; vt++) {
    uintx2 pkv;
    pkv[0] = pkrtz(accO[vt][0] * invl, accO[vt][1] * invl);
    pkv[1] = pkrtz(accO[vt][2] * invl, accO[vt][3] * invl);
    *(uintx2*)(orow + vt * 16 + quad * 4) = pkv;
  }
  if (quad == 0) {
    float* idx = side ? idxR : idxL;
    idx[p] = (float)(q & 127) - aC_all * invl;
  }
}

// ---------------------------------------------------------------------------
// MFMA up-projection + fused batch stats (R12).
// y[b,co,pos] = after[b,pos,:]·up_w[co,:] + up_b; per-channel Σy, Σy² go
// through in-register quad reduce -> LDS wave reduce -> 2 atomicAdd/ch.
// stats accumulators are zeroed by ra_projm block 0.
// ---------------------------------------------------------------------------
#define WSTR 136   // u16 stride (272B, 16B-aligned rows)

__global__ __launch_bounds__(256) void ra_upm(
    const u16* __restrict__ afterL, const u16* __restrict__ afterR,
    const float* __restrict__ w, const float* __restrict__ bias,
    u16* __restrict__ yL, u16* __restrict__ yR,
    float* __restrict__ stL, float* __restrict__ stR)
{
  __shared__ u16 w_lds[128 * WSTR];   // [co][r]; reused as float scratch
  const int tid  = threadIdx.x;
  const int bx   = blockIdx.x;
  const int side = bx >> 8;
  const int sbx  = bx & 255;
  const u16* __restrict__ after = side ? afterR : afterL;
  u16* __restrict__ y = side ? yR : yL;
  const int b    = sbx >> 6;
  const int pos0 = ((sbx >> 1) & 31) * 128;
  const int hc   = sbx & 1;
  const int wv   = tid >> 6;
  const int lane = tid & 63;
  const int ln16 = lane & 15;
  const int quad = lane >> 4;

  {
    const int co = tid >> 1, rh = (tid & 1) * 64;
    const float* wp = w + (size_t)(hc * 128 + co) * RP + rh;
    #pragma unroll
    for (int i = 0; i < 8; i++) {
      floatx4 f0 = *(const floatx4*)(wp + i * 8);
      floatx4 f1 = *(const floatx4*)(wp + i * 8 + 4);
      uintx4 v;
      v[0] = pk2h(f0[0], f0[1]); v[1] = pk2h(f0[2], f0[3]);
      v[2] = pk2h(f1[0], f1[1]); v[3] = pk2h(f1[2], f1[3]);
      *(uintx4*)&w_lds[co * WSTR + rh + i * 8] = v;
    }
  }
  __syncthreads();

  floatx4 acc[2][8];
  #pragma unroll
  for (int mt = 0; mt < 2; mt++)
    #pragma unroll
    for (int nt = 0; nt < 8; nt++) acc[mt][nt] = (floatx4)0.0f;

  #pragma unroll
  for (int kk = 0; kk < 4; kk++) {
    half8 a[2];
    #pragma unroll
    for (int mt = 0; mt < 2; mt++)
      a[mt] = as_h8(*(const uintx4*)(after +
          (size_t)(b * HW + pos0 + wv * 32 + mt * 16 + ln16) * RP + kk * 32 + quad * 8));
    #pragma unroll
    for (int nt = 0; nt < 8; nt++) {
      half8 bf = as_h8(*(const uintx4*)&w_lds[(nt * 16 + ln16) * WSTR + kk * 32 + quad * 8]);
      acc[0][nt] = __builtin_amdgcn_mfma_f32_16x16x32_f16(a[0], bf, acc[0][nt], 0, 0, 0);
      acc[1][nt] = __builtin_amdgcn_mfma_f32_16x16x32_f16(a[1], bf, acc[1][nt], 0, 0, 0);
    }
  }

  // y store + per-channel partials (this block: 128 pos of one b)
  float s_nt[8], q_nt[8];
  #pragma unroll
  for (int nt = 0; nt < 8; nt++) {
    const int co = hc * 128 + nt * 16 + ln16;
    const float bs = bias[co];
    float s = 0.f, sq = 0.f;
    #pragma unroll
    for (int mt = 0; mt < 2; mt++) {
      const int pv = pos0 + wv * 32 + mt * 16 + quad * 4;
      floatx4 v = acc[mt][nt];
      Pk4 pk;
      #pragma unroll
      for (int rr = 0; rr < 4; rr++) {
        const float yv = v[rr] + bs;
        s += yv; sq += yv * yv;
        pk.u[rr] = f2bf(yv);
      }
      *(uintx2*)(y + (size_t)(b * CB + co) * HW + pv) = pk.v;
    }
    s  += __shfl_xor(s, 16);  s  += __shfl_xor(s, 32);
    sq += __shfl_xor(sq, 16); sq += __shfl_xor(sq, 32);
    s_nt[nt] = s; q_nt[nt] = sq;
  }
  __syncthreads();              // all waves done reading w_lds
  float* scr = (float*)w_lds;   // [0..511]=s per (wv,co), [512..1023]=sq
  if (quad == 0) {
    #pragma unroll
    for (int nt = 0; nt < 8; nt++) {
      scr[wv * 128 + nt * 16 + ln16]       = s_nt[nt];
      scr[512 + wv * 128 + nt * 16 + ln16] = q_nt[nt];
    }
  }
  __syncthreads();
  if (tid < 128) {
    const float s  = scr[tid] + scr[128 + tid] + scr[256 + tid] + scr[384 + tid];
    const float sq = scr[512 + tid] + scr[640 + tid] + scr[768 + tid] + scr[896 + tid];
    float* stats = side ? stR : stL;
    atomicAdd(&stats[2 * (hc * 128 + tid)], s);
    atomicAdd(&stats[2 * (hc * 128 + tid) + 1], sq);
  }
}

// ---------------------------------------------------------------------------
// out = x + gamma*(y - mean)*rstd + beta. stats hold raw Σy, Σy².
// ---------------------------------------------------------------------------
__global__ __launch_bounds__(256) void ra_fin(
    const float* __restrict__ left, const float* __restrict__ right,
    const u16* __restrict__ yL, const u16* __restrict__ yR,
    const float* __restrict__ stL, const float* __restrict__ stR,
    const float* __restrict__ gamma, const float* __restrict__ beta,
    float* __restrict__ out)
{
  const size_t e = (size_t)blockIdx.x * 256 + threadIdx.x;  // global float4 idx
  const int side = (int)(e >> 20);
  const size_t e4 = e & 1048575;
  const int c = (int)((e4 >> 10) & 255);
  const float* x = side ? right : left;
  const u16* y = side ? yR : yL;
  const float* stats = side ? stR : stL;
  const float s = stats[2 * c], sq = stats[2 * c + 1];
  const float mean = s * (1.f / 16384.f);
  const float var  = sq * (1.f / 16384.f) - mean * mean;
  const float rstd = rsqrtf(var + EPSF);
  const float ga = gamma[c], be = beta[c];
  floatx4 xv = ((const floatx4*)x)[e4];
  uintx2 yv = ((const uintx2*)y)[e4];
  float f0 = bf2f((u16)(yv[0] & 0xffffu));
  float f1 = bf2f((u16)(yv[0] >> 16));
  float f2 = bf2f((u16)(yv[1] & 0xffffu));
  float f3 = bf2f((u16)(yv[1] >> 16));
  floatx4 o;
  o[0] = xv[0] + ga * ((f0 - mean) * rstd) + be;
  o[1] = xv[1] + ga * ((f1 - mean) * rstd) + be;
  o[2] = xv[2] + ga * ((f2 - mean) * rstd) + be;
  o[3] = xv[3] + ga * ((f3 - mean) * rstd) + be;
  ((floatx4*)out)[(size_t)side * 1048576 + e4] = o;
}

// ---------------------------------------------------------------------------
extern "C" void kernel_launch(void* const* d_in, const int* in_sizes, int n_in,
                              void* d_out, int out_size, void* d_ws, size_t ws_size,
                              hipStream_t stream)
{
  const float* left    = (const float*)d_in[0];
  const float* right   = (const float*)d_in[1];
  const float* pre_l   = (const float*)d_in[2];
  const float* pre_r   = (const float*)d_in[3];
  const float* query_l = (const float*)d_in[4];
  const float* key_l   = (const float*)d_in[5];
  const float* query_r = (const float*)d_in[6];
  const float* key_r   = (const float*)d_in[7];
  const float* theta_w = (const float*)d_in[8];
  const float* theta_b = (const float*)d_in[9];
  const float* phi_w   = (const float*)d_in[10];
  const float* phi_b   = (const float*)d_in[11];
  const float* g_w     = (const float*)d_in[12];
  const float* g_b     = (const float*)d_in[13];
  const float* up_w    = (const float*)d_in[14];
  const float* up_b    = (const float*)d_in[15];
  const float* bn_g    = (const float*)d_in[16];
  const float* bn_b    = (const float*)d_in[17];
  float* out = (float*)d_out;

  char* ws = (char*)d_ws;
  const size_t SZ = (size_t)4 * HW * RP * 2;  // 4 MiB (fp16 [4][4096][128])
  u16* thetaL = (u16*)(ws);
  u16* phiTL  = (u16*)(ws + 1 * SZ);
  u16* gTL    = (u16*)(ws + 2 * SZ);
  u16* thetaR = (u16*)(ws + 3 * SZ);
  u16* phiTR  = (u16*)(ws + 4 * SZ);
  u16* gTR    = (u16*)(ws + 5 * SZ);
  u16* afterL = (u16*)(ws + 6 * SZ);
  u16* afterR = (u16*)(ws + 7 * SZ);
  u16* yL     = (u16*)(ws + 8 * SZ);    // 8 MiB
  u16* yR     = (u16*)(ws + 10 * SZ);   // 8 MiB
  float* stL  = (float*)(ws + 12 * SZ);
  float* stR  = (float*)(ws + 12 * SZ + 2048);

  dim3 blk(256);
  // side L: x_q=left, x_kv=right, query_l, key_r; side R mirrored.
  ProjCfg6 pc;
  pc.c[0] = { left,  theta_w, theta_b, query_l, pre_l,   thetaL, 257, 0 };
  pc.c[1] = { right, phi_w,   phi_b,   key_r,   nullptr, phiTL,  256, 0 };
  pc.c[2] = { right, g_w,     g_b,     nullptr, nullptr, gTL,    256, 1 };
  pc.c[3] = { right, theta_w, theta_b, query_r, pre_r,   thetaR, 257, 0 };
  pc.c[4] = { left,  phi_w,   phi_b,   key_l,   nullptr, phiTR,  256, 0 };
  pc.c[5] = { left,  g_w,     g_b,     nullptr, nullptr, gTR,    256, 1 };
  ra_projm<<<768, blk, 0, stream>>>(pc, stL);

  ra_flash<<<512, blk, 0, stream>>>(thetaL, phiTL, gTL, thetaR, phiTR, gTR,
                                    afterL, afterR,
                                    out + 8388608, out + 8404992);
  ra_upm<<<512, blk, 0, stream>>>(afterL, afterR, up_w, up_b, yL, yR, stL, stR);
  ra_fin<<<8192, blk, 0, stream>>>(left, right, yL, yR, stL, stR, bn_g, bn_b, out);

  (void)in_sizes; (void)n_in; (void)out_size; (void)ws_size;
}